// Round 1
// baseline (1418.035 us; speedup 1.0000x reference)
//
#include <hip/hip_runtime.h>

#define D    256
#define NH   8
#define DH   32
#define NL   4
#define NP   4
#define DFF  1024
#define NQ   900
#define BS   4
#define LV   13294
#define MROWS (NQ*BS)   // 3600

// ---------------- elementwise add ----------------
__global__ void add_kernel(const float* __restrict__ a, const float* __restrict__ b,
                           float* __restrict__ out, int n) {
    int i = blockIdx.x * blockDim.x + threadIdx.x;
    if (i < n) out[i] = a[i] + b[i];
}

// ---------------- generic tiled f32 GEMM: Y[M,N] = X[M,K] @ W[K,N] + bias ----------------
template<bool RELU>
__global__ void gemm_kernel(const float* __restrict__ X, const float* __restrict__ W,
                            const float* __restrict__ bias, float* __restrict__ Y,
                            int M, int K, int N) {
    __shared__ float Xs[16][16];
    __shared__ float Ws[16][17];
    int tx = threadIdx.x & 15, ty = threadIdx.x >> 4;
    int row = blockIdx.y * 16 + ty;
    int col = blockIdx.x * 16 + tx;
    float acc = 0.f;
    for (int k0 = 0; k0 < K; k0 += 16) {
        Xs[ty][tx] = (row < M) ? X[row * K + k0 + tx] : 0.f;
        Ws[ty][tx] = W[(k0 + ty) * N + col];
        __syncthreads();
        #pragma unroll
        for (int kk = 0; kk < 16; ++kk) acc += Xs[ty][kk] * Ws[kk][tx];
        __syncthreads();
    }
    if (row < M) {
        acc += bias[col];
        if (RELU) acc = fmaxf(acc, 0.f);
        Y[row * N + col] = acc;
    }
}

// ---------------- self-attention: one block per (n,h,b), softmax over 900 keys ----------------
__global__ void sa_attn_kernel(const float* __restrict__ q, const float* __restrict__ k,
                               const float* __restrict__ v, float* __restrict__ o) {
    int n = blockIdx.x, h = blockIdx.y, b = blockIdx.z;
    int t = threadIdx.x;
    __shared__ float sc[NQ];
    __shared__ float qv[DH];
    __shared__ float red[8];
    __shared__ float pv[8][DH];
    if (t < DH) qv[t] = q[(n * BS + b) * D + h * DH + t];
    __syncthreads();
    const float scale = 0.17677669529663687f;  // 1/sqrt(32)
    for (int kk = t; kk < NQ; kk += 256) {
        const float* kp = k + (kk * BS + b) * D + h * DH;
        float s = 0.f;
        #pragma unroll
        for (int dd = 0; dd < DH; ++dd) s += qv[dd] * kp[dd];
        sc[kk] = s * scale;
    }
    __syncthreads();
    // block max
    float m = -1e30f;
    for (int kk = t; kk < NQ; kk += 256) m = fmaxf(m, sc[kk]);
    int lane = t & 63, wid = t >> 6;
    for (int off = 32; off; off >>= 1) m = fmaxf(m, __shfl_down(m, off));
    if (lane == 0) red[wid] = m;
    __syncthreads();
    if (t == 0) red[4] = fmaxf(fmaxf(red[0], red[1]), fmaxf(red[2], red[3]));
    __syncthreads();
    m = red[4];
    // exp + sum
    float sum = 0.f;
    for (int kk = t; kk < NQ; kk += 256) { float e = __expf(sc[kk] - m); sc[kk] = e; sum += e; }
    __syncthreads();
    for (int off = 32; off; off >>= 1) sum += __shfl_down(sum, off);
    if (lane == 0) red[wid] = sum;
    __syncthreads();
    if (t == 0) red[5] = red[0] + red[1] + red[2] + red[3];
    __syncthreads();
    float inv = 1.f / red[5];
    // PV: thread t -> dh = t&31, key-chunk = t>>5 (8 chunks)
    int dh = t & 31, ch = t >> 5;
    float acc = 0.f;
    for (int kk = ch; kk < NQ; kk += 8) acc += sc[kk] * v[(kk * BS + b) * D + h * DH + dh];
    pv[ch][dh] = acc;
    __syncthreads();
    if (t < DH) {
        float s2 = 0.f;
        #pragma unroll
        for (int c = 0; c < 8; ++c) s2 += pv[c][t];
        o[(n * BS + b) * D + h * DH + t] = s2 * inv;
    }
}

// ---------------- out = LayerNorm(x + y) * g + beta ; one block (256 thr) per row ----------------
__global__ void add_ln_kernel(const float* __restrict__ x, const float* __restrict__ y,
                              const float* __restrict__ g, const float* __restrict__ bt,
                              float* __restrict__ out) {
    int m = blockIdx.x, t = threadIdx.x;
    __shared__ float red[8];
    float v = x[m * D + t] + y[m * D + t];
    int lane = t & 63, wid = t >> 6;
    float s = v;
    for (int off = 32; off; off >>= 1) s += __shfl_down(s, off);
    if (lane == 0) red[wid] = s;
    __syncthreads();
    if (t == 0) red[4] = (red[0] + red[1] + red[2] + red[3]) * (1.f / D);
    __syncthreads();
    float mu = red[4];
    float d = v - mu;
    float s2 = d * d;
    __syncthreads();
    for (int off = 32; off; off >>= 1) s2 += __shfl_down(s2, off);
    if (lane == 0) red[wid] = s2;
    __syncthreads();
    if (t == 0) red[5] = rsqrtf((red[0] + red[1] + red[2] + red[3]) * (1.f / D) + 1e-5f);
    __syncthreads();
    out[m * D + t] = d * red[5] * g[t] + bt[t];
}

// ---------------- softmax over NL*NP=16 per (m,h), in place ----------------
__global__ void aw_softmax_kernel(float* __restrict__ aw) {
    int i = blockIdx.x * blockDim.x + threadIdx.x;
    if (i >= MROWS * NH) return;
    float* p = aw + (size_t)i * 16;   // aw[m*128 + h*16 + j], i = m*8+h
    float mx = p[0];
    #pragma unroll
    for (int j = 1; j < 16; ++j) mx = fmaxf(mx, p[j]);
    float e[16], s = 0.f;
    #pragma unroll
    for (int j = 0; j < 16; ++j) { e[j] = __expf(p[j] - mx); s += e[j]; }
    float inv = 1.f / s;
    #pragma unroll
    for (int j = 0; j < 16; ++j) p[j] = e[j] * inv;
}

// ---------------- deformable sampling: block per (n,b); thread = h*32+dh ----------------
__global__ void deform_kernel(const float* __restrict__ value, const float* __restrict__ offs,
                              const float* __restrict__ aw, const float* __restrict__ refp,
                              const int* __restrict__ shapes, const int* __restrict__ lsi,
                              float* __restrict__ out) {
    int n = blockIdx.x, b = blockIdx.y;
    int t = threadIdx.x, h = t >> 5, dh = t & 31;
    int m = n * BS + b;
    float acc = 0.f;
    #pragma unroll
    for (int l = 0; l < NL; ++l) {
        int Hl = shapes[l * 2], Wl = shapes[l * 2 + 1], s = lsi[l];
        float Wf = (float)Wl, Hf = (float)Hl;
        float rx = refp[(m * NL + l) * 2 + 0];
        float ry = refp[(m * NL + l) * 2 + 1];
        #pragma unroll
        for (int p = 0; p < NP; ++p) {
            int oc = ((h * NL + l) * NP + p) * 2;
            float ox = offs[m * 256 + oc];
            float oy = offs[m * 256 + oc + 1];
            float w = aw[m * 128 + (h * NL + l) * NP + p];
            float locx = rx + ox / Wf;
            float locy = ry + oy / Hf;
            float x = locx * Wf - 0.5f;
            float y = locy * Hf - 0.5f;
            float x0 = floorf(x), y0 = floorf(y);
            float lx = x - x0, ly = y - y0;
            int xi = (int)x0, yi = (int)y0;
            #pragma unroll
            for (int cy = 0; cy < 2; ++cy) {
                #pragma unroll
                for (int cx = 0; cx < 2; ++cx) {
                    int xx = xi + cx, yy = yi + cy;
                    if (xx >= 0 && xx < Wl && yy >= 0 && yy < Hl) {
                        float cw = (cx ? lx : 1.f - lx) * (cy ? ly : 1.f - ly);
                        acc += w * cw * value[((size_t)(s + yy * Wl + xx) * BS + b) * D + h * DH + dh];
                    }
                }
            }
        }
    }
    out[m * D + h * DH + dh] = acc;
}

extern "C" void kernel_launch(void* const* d_in, const int* in_sizes, int n_in,
                              void* d_out, int out_size, void* d_ws, size_t ws_size,
                              hipStream_t stream) {
    const float* tgt    = (const float*)d_in[0];
    const float* pos    = (const float*)d_in[1];
    const float* refp   = (const float*)d_in[2];
    const float* memory = (const float*)d_in[3];
    const int*   shapes = (const int*)d_in[4];
    const int*   lsi    = (const int*)d_in[5];
    const float* sa_wq = (const float*)d_in[6],  *sa_bq = (const float*)d_in[7];
    const float* sa_wk = (const float*)d_in[8],  *sa_bk = (const float*)d_in[9];
    const float* sa_wv = (const float*)d_in[10], *sa_bv = (const float*)d_in[11];
    const float* sa_wo = (const float*)d_in[12], *sa_bo = (const float*)d_in[13];
    const float* ln2_g = (const float*)d_in[14], *ln2_b = (const float*)d_in[15];
    const float* ca_wval = (const float*)d_in[16], *ca_bval = (const float*)d_in[17];
    const float* ca_woff = (const float*)d_in[18], *ca_boff = (const float*)d_in[19];
    const float* ca_wattn = (const float*)d_in[20], *ca_battn = (const float*)d_in[21];
    const float* ca_wout = (const float*)d_in[22], *ca_bout = (const float*)d_in[23];
    const float* ln1_g = (const float*)d_in[24], *ln1_b = (const float*)d_in[25];
    const float* ffn_w1 = (const float*)d_in[26], *ffn_b1 = (const float*)d_in[27];
    const float* ffn_w2 = (const float*)d_in[28], *ffn_b2 = (const float*)d_in[29];
    const float* ln3_g = (const float*)d_in[30], *ln3_b = (const float*)d_in[31];
    float* out = (float*)d_out;

    // ---- workspace carve-up (floats). Reuse buffers across phases. ----
    float* ws = (float*)d_ws;
    size_t off = 0;
    auto alloc = [&](size_t n) { float* p = ws + off; off += n; return p; };
    const size_t MD = (size_t)MROWS * D;           // 921600
    float* x     = alloc(MD);                      // tgt+pos, later query=tgt1+pos
    float* q     = alloc(MD);                      // q proj, later samp output
    float* k     = alloc(MD);                      // k proj, later offsets
    float* v     = alloc(MD);                      // v proj, later aw (only 460800 used)
    float* o     = alloc(MD);                      // attn out, later ca out-proj result
    float* o2    = alloc(MD);                      // o-proj, later ffn out
    float* tgt1  = alloc(MD);
    float* tgt2  = alloc(MD);
    float* value = alloc((size_t)LV * BS * D);     // 13,613,056 ; later reused for ffn hidden
    float* offs = k;
    float* aw   = v;
    float* samp = q;
    float* cao  = o;
    float* hbuf = value + 0;                       // value free after deform; DFF*MROWS=3.69M fits
    float* ffo  = o2;
    (void)ws_size; (void)in_sizes; (void)n_in; (void)out_size;

    dim3 b256(256);

    // ---- self attention ----
    add_kernel<<<dim3((MD + 255) / 256), b256, 0, stream>>>(tgt, pos, x, (int)MD);
    gemm_kernel<false><<<dim3(D / 16, MROWS / 16), b256, 0, stream>>>(x, sa_wq, sa_bq, q, MROWS, D, D);
    gemm_kernel<false><<<dim3(D / 16, MROWS / 16), b256, 0, stream>>>(x, sa_wk, sa_bk, k, MROWS, D, D);
    gemm_kernel<false><<<dim3(D / 16, MROWS / 16), b256, 0, stream>>>(tgt, sa_wv, sa_bv, v, MROWS, D, D);
    sa_attn_kernel<<<dim3(NQ, NH, BS), b256, 0, stream>>>(q, k, v, o);
    gemm_kernel<false><<<dim3(D / 16, MROWS / 16), b256, 0, stream>>>(o, sa_wo, sa_bo, o2, MROWS, D, D);
    add_ln_kernel<<<dim3(MROWS), b256, 0, stream>>>(tgt, o2, ln2_g, ln2_b, tgt1);

    // ---- MSDeformAttn cross attention ----
    add_kernel<<<dim3((MD + 255) / 256), b256, 0, stream>>>(tgt1, pos, x, (int)MD);   // query
    gemm_kernel<false><<<dim3(D / 16, (LV * BS + 15) / 16), b256, 0, stream>>>(
        memory, ca_wval, ca_bval, value, LV * BS, D, D);
    gemm_kernel<false><<<dim3(256 / 16, MROWS / 16), b256, 0, stream>>>(x, ca_woff, ca_boff, offs, MROWS, D, NH * NL * NP * 2);
    gemm_kernel<false><<<dim3(128 / 16, MROWS / 16), b256, 0, stream>>>(x, ca_wattn, ca_battn, aw, MROWS, D, NH * NL * NP);
    aw_softmax_kernel<<<dim3((MROWS * NH + 255) / 256), b256, 0, stream>>>(aw);
    deform_kernel<<<dim3(NQ, BS), b256, 0, stream>>>(value, offs, aw, refp, shapes, lsi, samp);
    gemm_kernel<false><<<dim3(D / 16, MROWS / 16), b256, 0, stream>>>(samp, ca_wout, ca_bout, cao, MROWS, D, D);
    add_ln_kernel<<<dim3(MROWS), b256, 0, stream>>>(tgt1, cao, ln1_g, ln1_b, tgt2);

    // ---- FFN ----
    gemm_kernel<true><<<dim3(DFF / 16, MROWS / 16), b256, 0, stream>>>(tgt2, ffn_w1, ffn_b1, hbuf, MROWS, D, DFF);
    gemm_kernel<false><<<dim3(D / 16, MROWS / 16), b256, 0, stream>>>(hbuf, ffn_w2, ffn_b2, ffo, MROWS, DFF, D);
    add_ln_kernel<<<dim3(MROWS), b256, 0, stream>>>(tgt2, ffo, ln3_g, ln3_b, out);
}

// Round 2
// 847.106 us; speedup vs baseline: 1.6740x; 1.6740x over previous
//
#include <hip/hip_runtime.h>

#define D    256
#define NH   8
#define DH   32
#define NL   4
#define NP   4
#define DFF  1024
#define NQ   900
#define BS   4
#define LV   13294
#define MROWS (NQ*BS)   // 3600

// ---------------- elementwise add ----------------
__global__ void add_kernel(const float* __restrict__ a, const float* __restrict__ b,
                           float* __restrict__ out, int n) {
    int i = blockIdx.x * blockDim.x + threadIdx.x;
    if (i < n) out[i] = a[i] + b[i];
}

// ---------------- f32 GEMM: Y[M,N] = X[M,K] @ W[K,N] + bias ; 64x64 tile, 4x4/thread ----------------
template<bool RELU>
__global__ void gemm64_kernel(const float* __restrict__ X, const float* __restrict__ W,
                              const float* __restrict__ bias, float* __restrict__ Y,
                              int M, int K, int N) {
    __shared__ float XsT[32][68];   // [k][m], pad 68 -> float4 reads conflict-free
    __shared__ float Ws[32][68];    // [k][n]
    int t = threadIdx.x;
    int tx = t & 15, ty = t >> 4;
    int row0 = blockIdx.y * 64, col0 = blockIdx.x * 64;
    float acc[4][4] = {};
    for (int k0 = 0; k0 < K; k0 += 32) {
        #pragma unroll
        for (int i = 0; i < 8; ++i) {
            int idx = t + i * 256;            // 2048 = 64m x 32k
            int kk = idx & 31, mm = idx >> 5;
            int gm = row0 + mm;
            XsT[kk][mm] = (gm < M) ? X[(size_t)gm * K + k0 + kk] : 0.f;
        }
        #pragma unroll
        for (int i = 0; i < 8; ++i) {
            int idx = t + i * 256;            // 2048 = 32k x 64n
            int nn = idx & 63, kk = idx >> 6;
            Ws[kk][nn] = W[(size_t)(k0 + kk) * N + col0 + nn];
        }
        __syncthreads();
        #pragma unroll
        for (int kk = 0; kk < 32; ++kk) {
            float4 a4 = *(const float4*)&XsT[kk][ty * 4];
            float4 b4 = *(const float4*)&Ws[kk][tx * 4];
            float a[4] = {a4.x, a4.y, a4.z, a4.w};
            float bb[4] = {b4.x, b4.y, b4.z, b4.w};
            #pragma unroll
            for (int i2 = 0; i2 < 4; ++i2)
                #pragma unroll
                for (int j = 0; j < 4; ++j) acc[i2][j] += a[i2] * bb[j];
        }
        __syncthreads();
    }
    #pragma unroll
    for (int i2 = 0; i2 < 4; ++i2) {
        int gr = row0 + ty * 4 + i2;
        if (gr < M) {
            float4 o4;
            float* op = (float*)&o4;
            #pragma unroll
            for (int j = 0; j < 4; ++j) {
                float vv = acc[i2][j] + bias[col0 + tx * 4 + j];
                if (RELU) vv = fmaxf(vv, 0.f);
                op[j] = vv;
            }
            *(float4*)&Y[(size_t)gr * N + col0 + tx * 4] = o4;
        }
    }
}

// ---------------- flash-style self-attention ----------------
// block per (qtile, h, b): 64 queries, loop K/V tiles of 64, online softmax.
__global__ void sa_flash_kernel(const float* __restrict__ q, const float* __restrict__ k,
                                const float* __restrict__ v, float* __restrict__ o) {
    int qt = blockIdx.x, h = blockIdx.y, b = blockIdx.z;
    int q0 = qt * 64;
    __shared__ float Qs[64][33];
    __shared__ float Ks[64][33];
    __shared__ float Vs[64][33];
    __shared__ float Ps[64][68];            // pad 68 -> aligned float4 rows
    __shared__ float rowm[64], rowl[64], rowscale[64];
    int t = threadIdx.x;
    int tx = t & 15, ty = t >> 4;           // score phase: 4 rows x 4 cols per thread
    const float scale = 0.17677669529663687f;  // 1/sqrt(32), folded into Q

    #pragma unroll
    for (int i = 0; i < 8; ++i) {
        int s = t + i * 256; int r = s >> 5, d = s & 31;
        int qn = q0 + r;
        Qs[r][d] = (qn < NQ) ? q[((size_t)qn * BS + b) * D + h * DH + d] * scale : 0.f;
    }
    if (t < 64) { rowm[t] = -1e30f; rowl[t] = 0.f; rowscale[t] = 0.f; }
    int r0 = (t >> 5) * 8;                  // PV phase: 8 rows, d = t&31
    int dd = t & 31;
    float acc[8] = {0.f, 0.f, 0.f, 0.f, 0.f, 0.f, 0.f, 0.f};
    __syncthreads();

    for (int k0 = 0; k0 < NQ; k0 += 64) {
        #pragma unroll
        for (int i = 0; i < 8; ++i) {
            int s = t + i * 256; int r = s >> 5, d = s & 31;
            int kn = k0 + r;
            Ks[r][d] = (kn < NQ) ? k[((size_t)kn * BS + b) * D + h * DH + d] : 0.f;
            Vs[r][d] = (kn < NQ) ? v[((size_t)kn * BS + b) * D + h * DH + d] : 0.f;
        }
        __syncthreads();

        // scores S[ty*4+i][tx*4+j]
        float s4[4][4] = {};
        #pragma unroll
        for (int d = 0; d < 32; ++d) {
            float a_[4], b_[4];
            #pragma unroll
            for (int i = 0; i < 4; ++i) a_[i] = Qs[ty * 4 + i][d];
            #pragma unroll
            for (int j = 0; j < 4; ++j) b_[j] = Ks[tx * 4 + j][d];
            #pragma unroll
            for (int i = 0; i < 4; ++i)
                #pragma unroll
                for (int j = 0; j < 4; ++j) s4[i][j] += a_[i] * b_[j];
        }
        int kvalid = NQ - k0;                // mask key tail
        #pragma unroll
        for (int j = 0; j < 4; ++j)
            if (tx * 4 + j >= kvalid) {
                #pragma unroll
                for (int i = 0; i < 4; ++i) s4[i][j] = -1e30f;
            }

        // per-row tile max via shfl_xor over the 16 threads sharing a row
        float lm[4];
        #pragma unroll
        for (int i = 0; i < 4; ++i)
            lm[i] = fmaxf(fmaxf(s4[i][0], s4[i][1]), fmaxf(s4[i][2], s4[i][3]));
        #pragma unroll
        for (int m = 1; m <= 8; m <<= 1)
            #pragma unroll
            for (int i = 0; i < 4; ++i) lm[i] = fmaxf(lm[i], __shfl_xor(lm[i], m));

        float ts[4];
        #pragma unroll
        for (int i = 0; i < 4; ++i) {
            int r = ty * 4 + i;
            float mold = rowm[r];
            float newm = fmaxf(mold, lm[i]);
            float4 p4;
            float* pp = (float*)&p4;
            float psum = 0.f;
            #pragma unroll
            for (int j = 0; j < 4; ++j) { pp[j] = __expf(s4[i][j] - newm); psum += pp[j]; }
            *(float4*)&Ps[r][tx * 4] = p4;
            ts[i] = psum;
            s4[i][0] = newm;                 // stash newm
            s4[i][1] = __expf(mold - newm);  // stash scale
        }
        #pragma unroll
        for (int m = 1; m <= 8; m <<= 1)
            #pragma unroll
            for (int i = 0; i < 4; ++i) ts[i] += __shfl_xor(ts[i], m);
        if (tx == 0) {
            #pragma unroll
            for (int i = 0; i < 4; ++i) {
                int r = ty * 4 + i;
                rowm[r] = s4[i][0];
                rowl[r] = rowl[r] * s4[i][1] + ts[i];
                rowscale[r] = s4[i][1];
            }
        }
        __syncthreads();

        // PV: acc[i] for (r0+i, dd)
        #pragma unroll
        for (int i = 0; i < 8; ++i) acc[i] *= rowscale[r0 + i];
        for (int c0 = 0; c0 < 64; c0 += 16) {
            float vv[16];
            #pragma unroll
            for (int c = 0; c < 16; ++c) vv[c] = Vs[c0 + c][dd];
            #pragma unroll
            for (int i = 0; i < 8; ++i) {
                #pragma unroll
                for (int c4 = 0; c4 < 4; ++c4) {
                    float4 p4 = *(const float4*)&Ps[r0 + i][c0 + c4 * 4];
                    acc[i] += p4.x * vv[c4 * 4] + p4.y * vv[c4 * 4 + 1]
                            + p4.z * vv[c4 * 4 + 2] + p4.w * vv[c4 * 4 + 3];
                }
            }
        }
        __syncthreads();
    }
    #pragma unroll
    for (int i = 0; i < 8; ++i) {
        int qn = q0 + r0 + i;
        if (qn < NQ) o[((size_t)qn * BS + b) * D + h * DH + dd] = acc[i] / rowl[r0 + i];
    }
}

// ---------------- out = LayerNorm(x + y) * g + beta ; one block (256 thr) per row ----------------
__global__ void add_ln_kernel(const float* __restrict__ x, const float* __restrict__ y,
                              const float* __restrict__ g, const float* __restrict__ bt,
                              float* __restrict__ out) {
    int m = blockIdx.x, t = threadIdx.x;
    __shared__ float red[8];
    float v = x[m * D + t] + y[m * D + t];
    int lane = t & 63, wid = t >> 6;
    float s = v;
    for (int off = 32; off; off >>= 1) s += __shfl_down(s, off);
    if (lane == 0) red[wid] = s;
    __syncthreads();
    if (t == 0) red[4] = (red[0] + red[1] + red[2] + red[3]) * (1.f / D);
    __syncthreads();
    float mu = red[4];
    float d = v - mu;
    float s2 = d * d;
    __syncthreads();
    for (int off = 32; off; off >>= 1) s2 += __shfl_down(s2, off);
    if (lane == 0) red[wid] = s2;
    __syncthreads();
    if (t == 0) red[5] = rsqrtf((red[0] + red[1] + red[2] + red[3]) * (1.f / D) + 1e-5f);
    __syncthreads();
    out[m * D + t] = d * red[5] * g[t] + bt[t];
}

// ---------------- softmax over NL*NP=16 per (m,h), in place ----------------
__global__ void aw_softmax_kernel(float* __restrict__ aw) {
    int i = blockIdx.x * blockDim.x + threadIdx.x;
    if (i >= MROWS * NH) return;
    float* p = aw + (size_t)i * 16;
    float mx = p[0];
    #pragma unroll
    for (int j = 1; j < 16; ++j) mx = fmaxf(mx, p[j]);
    float e[16], s = 0.f;
    #pragma unroll
    for (int j = 0; j < 16; ++j) { e[j] = __expf(p[j] - mx); s += e[j]; }
    float inv = 1.f / s;
    #pragma unroll
    for (int j = 0; j < 16; ++j) p[j] = e[j] * inv;
}

// ---------------- deformable sampling: block per (n,b); thread = h*32+dh ----------------
__global__ void deform_kernel(const float* __restrict__ value, const float* __restrict__ offs,
                              const float* __restrict__ aw, const float* __restrict__ refp,
                              const int* __restrict__ shapes, const int* __restrict__ lsi,
                              float* __restrict__ out) {
    int n = blockIdx.x, b = blockIdx.y;
    int t = threadIdx.x, h = t >> 5, dh = t & 31;
    int m = n * BS + b;
    float acc = 0.f;
    #pragma unroll
    for (int l = 0; l < NL; ++l) {
        int Hl = shapes[l * 2], Wl = shapes[l * 2 + 1], s = lsi[l];
        float Wf = (float)Wl, Hf = (float)Hl;
        float rx = refp[(m * NL + l) * 2 + 0];
        float ry = refp[(m * NL + l) * 2 + 1];
        #pragma unroll
        for (int p = 0; p < NP; ++p) {
            int oc = ((h * NL + l) * NP + p) * 2;
            float ox = offs[m * 256 + oc];
            float oy = offs[m * 256 + oc + 1];
            float w = aw[m * 128 + (h * NL + l) * NP + p];
            float locx = rx + ox / Wf;
            float locy = ry + oy / Hf;
            float x = locx * Wf - 0.5f;
            float y = locy * Hf - 0.5f;
            float x0 = floorf(x), y0 = floorf(y);
            float lx = x - x0, ly = y - y0;
            int xi = (int)x0, yi = (int)y0;
            #pragma unroll
            for (int cy = 0; cy < 2; ++cy) {
                #pragma unroll
                for (int cx = 0; cx < 2; ++cx) {
                    int xx = xi + cx, yy = yi + cy;
                    if (xx >= 0 && xx < Wl && yy >= 0 && yy < Hl) {
                        float cw = (cx ? lx : 1.f - lx) * (cy ? ly : 1.f - ly);
                        acc += w * cw * value[((size_t)(s + yy * Wl + xx) * BS + b) * D + h * DH + dh];
                    }
                }
            }
        }
    }
    out[m * D + h * DH + dh] = acc;
}

extern "C" void kernel_launch(void* const* d_in, const int* in_sizes, int n_in,
                              void* d_out, int out_size, void* d_ws, size_t ws_size,
                              hipStream_t stream) {
    const float* tgt    = (const float*)d_in[0];
    const float* pos    = (const float*)d_in[1];
    const float* refp   = (const float*)d_in[2];
    const float* memory = (const float*)d_in[3];
    const int*   shapes = (const int*)d_in[4];
    const int*   lsi    = (const int*)d_in[5];
    const float* sa_wq = (const float*)d_in[6],  *sa_bq = (const float*)d_in[7];
    const float* sa_wk = (const float*)d_in[8],  *sa_bk = (const float*)d_in[9];
    const float* sa_wv = (const float*)d_in[10], *sa_bv = (const float*)d_in[11];
    const float* sa_wo = (const float*)d_in[12], *sa_bo = (const float*)d_in[13];
    const float* ln2_g = (const float*)d_in[14], *ln2_b = (const float*)d_in[15];
    const float* ca_wval = (const float*)d_in[16], *ca_bval = (const float*)d_in[17];
    const float* ca_woff = (const float*)d_in[18], *ca_boff = (const float*)d_in[19];
    const float* ca_wattn = (const float*)d_in[20], *ca_battn = (const float*)d_in[21];
    const float* ca_wout = (const float*)d_in[22], *ca_bout = (const float*)d_in[23];
    const float* ln1_g = (const float*)d_in[24], *ln1_b = (const float*)d_in[25];
    const float* ffn_w1 = (const float*)d_in[26], *ffn_b1 = (const float*)d_in[27];
    const float* ffn_w2 = (const float*)d_in[28], *ffn_b2 = (const float*)d_in[29];
    const float* ln3_g = (const float*)d_in[30], *ln3_b = (const float*)d_in[31];
    float* out = (float*)d_out;

    float* ws = (float*)d_ws;
    size_t off = 0;
    auto alloc = [&](size_t n) { float* p = ws + off; off += n; return p; };
    const size_t MD = (size_t)MROWS * D;
    float* x     = alloc(MD);
    float* q     = alloc(MD);
    float* k     = alloc(MD);
    float* v     = alloc(MD);
    float* o     = alloc(MD);
    float* o2    = alloc(MD);
    float* tgt1  = alloc(MD);
    float* tgt2  = alloc(MD);
    float* value = alloc((size_t)LV * BS * D);
    float* offs = k;
    float* aw   = v;
    float* samp = q;
    float* cao  = o;
    float* hbuf = value;
    float* ffo  = o2;
    (void)ws_size; (void)in_sizes; (void)n_in; (void)out_size;

    dim3 b256(256);

    // ---- self attention ----
    add_kernel<<<dim3((MD + 255) / 256), b256, 0, stream>>>(tgt, pos, x, (int)MD);
    gemm64_kernel<false><<<dim3(D / 64, (MROWS + 63) / 64), b256, 0, stream>>>(x, sa_wq, sa_bq, q, MROWS, D, D);
    gemm64_kernel<false><<<dim3(D / 64, (MROWS + 63) / 64), b256, 0, stream>>>(x, sa_wk, sa_bk, k, MROWS, D, D);
    gemm64_kernel<false><<<dim3(D / 64, (MROWS + 63) / 64), b256, 0, stream>>>(tgt, sa_wv, sa_bv, v, MROWS, D, D);
    sa_flash_kernel<<<dim3((NQ + 63) / 64, NH, BS), b256, 0, stream>>>(q, k, v, o);
    gemm64_kernel<false><<<dim3(D / 64, (MROWS + 63) / 64), b256, 0, stream>>>(o, sa_wo, sa_bo, o2, MROWS, D, D);
    add_ln_kernel<<<dim3(MROWS), b256, 0, stream>>>(tgt, o2, ln2_g, ln2_b, tgt1);

    // ---- MSDeformAttn cross attention ----
    add_kernel<<<dim3((MD + 255) / 256), b256, 0, stream>>>(tgt1, pos, x, (int)MD);
    gemm64_kernel<false><<<dim3(D / 64, (LV * BS + 63) / 64), b256, 0, stream>>>(
        memory, ca_wval, ca_bval, value, LV * BS, D, D);
    gemm64_kernel<false><<<dim3(256 / 64, (MROWS + 63) / 64), b256, 0, stream>>>(x, ca_woff, ca_boff, offs, MROWS, D, NH * NL * NP * 2);
    gemm64_kernel<false><<<dim3(128 / 64, (MROWS + 63) / 64), b256, 0, stream>>>(x, ca_wattn, ca_battn, aw, MROWS, D, NH * NL * NP);
    aw_softmax_kernel<<<dim3((MROWS * NH + 255) / 256), b256, 0, stream>>>(aw);
    deform_kernel<<<dim3(NQ, BS), b256, 0, stream>>>(value, offs, aw, refp, shapes, lsi, samp);
    gemm64_kernel<false><<<dim3(D / 64, (MROWS + 63) / 64), b256, 0, stream>>>(samp, ca_wout, ca_bout, cao, MROWS, D, D);
    add_ln_kernel<<<dim3(MROWS), b256, 0, stream>>>(tgt1, cao, ln1_g, ln1_b, tgt2);

    // ---- FFN ----
    gemm64_kernel<true><<<dim3(DFF / 64, (MROWS + 63) / 64), b256, 0, stream>>>(tgt2, ffn_w1, ffn_b1, hbuf, MROWS, D, DFF);
    gemm64_kernel<false><<<dim3(D / 64, (MROWS + 63) / 64), b256, 0, stream>>>(hbuf, ffn_w2, ffn_b2, ffo, MROWS, DFF, D);
    add_ln_kernel<<<dim3(MROWS), b256, 0, stream>>>(tgt2, ffo, ln3_g, ln3_b, out);
}

// Round 3
// 388.828 us; speedup vs baseline: 3.6469x; 2.1786x over previous
//
#include <hip/hip_runtime.h>

#define D    256
#define NH   8
#define DH   32
#define NL   4
#define NP   4
#define DFF  1024
#define NQ   900
#define BS   4
#define LV   13294
#define MROWS (NQ*BS)   // 3600

typedef short bf16x8 __attribute__((ext_vector_type(8)));
typedef float f32x4  __attribute__((ext_vector_type(4)));

__device__ inline ushort f2bf(float f) {
    unsigned u = __float_as_uint(f);
    unsigned r = (u + 0x7fffu + ((u >> 16) & 1u)) >> 16;
    return (ushort)r;
}

// ---------------- elementwise add ----------------
__global__ void add_kernel(const float* __restrict__ a, const float* __restrict__ b,
                           float* __restrict__ out, int n) {
    int i = blockIdx.x * blockDim.x + threadIdx.x;
    if (i < n) out[i] = a[i] + b[i];
}

// ---------------- weight transpose+convert: W[K][N] f32 -> Wt[N][K] bf16 ----------------
__global__ void wt_transpose_kernel(
    const float* w0, const float* w1, const float* w2, const float* w3, const float* w4,
    const float* w5, const float* w6, const float* w7, const float* w8, const float* w9,
    ushort* o0, ushort* o1, ushort* o2, ushort* o3, ushort* o4,
    ushort* o5, ushort* o6, ushort* o7, ushort* o8, ushort* o9) {
    __shared__ float Ts[32][33];
    int z = blockIdx.z;
    const float* src; ushort* dst; int K, N;
    switch (z) {
        case 0: src = w0; dst = o0; K = 256;  N = 256;  break;
        case 1: src = w1; dst = o1; K = 256;  N = 256;  break;
        case 2: src = w2; dst = o2; K = 256;  N = 256;  break;
        case 3: src = w3; dst = o3; K = 256;  N = 256;  break;
        case 4: src = w4; dst = o4; K = 256;  N = 256;  break;
        case 5: src = w5; dst = o5; K = 256;  N = 256;  break;
        case 6: src = w6; dst = o6; K = 256;  N = 128;  break;
        case 7: src = w7; dst = o7; K = 256;  N = 256;  break;
        case 8: src = w8; dst = o8; K = 256;  N = 1024; break;
        default:src = w9; dst = o9; K = 1024; N = 256;  break;
    }
    int tiles_n = N >> 5;
    int tile = blockIdx.x;
    int tx = tile % tiles_n, ty = tile / tiles_n;
    if (ty >= (K >> 5)) return;
    int n0 = tx * 32, k0 = ty * 32;
    int t = threadIdx.x;
    #pragma unroll
    for (int i = 0; i < 4; ++i) {
        int e = t + i * 256; int r = e >> 5, c = e & 31;
        Ts[r][c] = src[(size_t)(k0 + r) * N + n0 + c];
    }
    __syncthreads();
    #pragma unroll
    for (int i = 0; i < 4; ++i) {
        int e = t + i * 256; int r = e >> 5, c = e & 31;
        dst[(size_t)(n0 + r) * K + k0 + c] = f2bf(Ts[c][r]);
    }
}

// ---------------- bf16 MFMA GEMM: Y[M,N] = X[M,K](f32) @ Wt[N,K](bf16)^T + bias ----------------
// 128x128 tile, 4 waves (2x2 of 64x64), BK=32, 16x16x32 MFMA.
template<bool RELU>
__global__ __launch_bounds__(256, 2)
void gemm_mfma_kernel(const float* __restrict__ X, const ushort* __restrict__ Wt,
                      const float* __restrict__ bias, float* __restrict__ Y,
                      int M, int K, int N) {
    __shared__ ushort As[128 * 40];   // [m][k] pad 40 -> bank-balanced b128
    __shared__ ushort Bs[128 * 40];   // [n][k]
    const int t = threadIdx.x;
    const int w = t >> 6, lane = t & 63;
    const int wr = w >> 1, wc = w & 1;
    const int l15 = lane & 15, kb = lane >> 4;
    const int row0 = blockIdx.y * 128, col0 = blockIdx.x * 128;
    f32x4 acc[4][4];
    #pragma unroll
    for (int i = 0; i < 4; ++i)
        #pragma unroll
        for (int j = 0; j < 4; ++j) acc[i][j] = (f32x4){0.f, 0.f, 0.f, 0.f};

    for (int k0 = 0; k0 < K; k0 += 32) {
        #pragma unroll
        for (int i = 0; i < 4; ++i) {
            int e = t + i * 256; int row = e >> 3, c4 = e & 7;
            int gr = row0 + row;
            float4 xv = make_float4(0.f, 0.f, 0.f, 0.f);
            if (gr < M) xv = *(const float4*)&X[(size_t)gr * K + k0 + c4 * 4];
            uint2 pk;
            pk.x = (unsigned)f2bf(xv.x) | ((unsigned)f2bf(xv.y) << 16);
            pk.y = (unsigned)f2bf(xv.z) | ((unsigned)f2bf(xv.w) << 16);
            *(uint2*)&As[row * 40 + c4 * 4] = pk;
        }
        #pragma unroll
        for (int i = 0; i < 4; ++i) {
            int e = t + i * 256; int row = e >> 3, c4 = e & 7;
            *(uint2*)&Bs[row * 40 + c4 * 4] =
                *(const uint2*)&Wt[(size_t)(col0 + row) * K + k0 + c4 * 4];
        }
        __syncthreads();
        bf16x8 af[4], bf[4];
        #pragma unroll
        for (int i = 0; i < 4; ++i)
            af[i] = *(const bf16x8*)&As[(wr * 64 + i * 16 + l15) * 40 + kb * 8];
        #pragma unroll
        for (int j = 0; j < 4; ++j)
            bf[j] = *(const bf16x8*)&Bs[(wc * 64 + j * 16 + l15) * 40 + kb * 8];
        #pragma unroll
        for (int i = 0; i < 4; ++i)
            #pragma unroll
            for (int j = 0; j < 4; ++j)
                acc[i][j] = __builtin_amdgcn_mfma_f32_16x16x32_bf16(af[i], bf[j], acc[i][j], 0, 0, 0);
        __syncthreads();
    }
    // C/D layout: col = lane&15, row = (lane>>4)*4 + reg
    #pragma unroll
    for (int i = 0; i < 4; ++i) {
        #pragma unroll
        for (int j = 0; j < 4; ++j) {
            int gcol = col0 + wc * 64 + j * 16 + l15;
            float bv = bias[gcol];
            #pragma unroll
            for (int r = 0; r < 4; ++r) {
                int grow = row0 + wr * 64 + i * 16 + kb * 4 + r;
                if (grow < M) {
                    float vv = acc[i][j][r] + bv;
                    if (RELU) vv = fmaxf(vv, 0.f);
                    Y[(size_t)grow * N + gcol] = vv;
                }
            }
        }
    }
}

// ---------------- MFMA flash self-attention ----------------
// block per (qtile64, h, b); 4 waves, wave w owns q rows [w*16, w*16+16).
__global__ __launch_bounds__(256, 2)
void sa_mfma_kernel(const float* __restrict__ q, const float* __restrict__ k,
                    const float* __restrict__ v, float* __restrict__ o) {
    __shared__ ushort Qs[64 * 40];
    __shared__ ushort Ks[64 * 40];
    __shared__ ushort Vt[32 * 72];     // [d][kidx] pad 72
    __shared__ ushort Pw[4 * 16 * 72]; // per-wave P tile [16 q][64 kidx] pad 72
    const int qt = blockIdx.x, h = blockIdx.y, b = blockIdx.z;
    const int q0 = qt * 64;
    const int t = threadIdx.x;
    const int w = t >> 6, lane = t & 63;
    const int l15 = lane & 15, kb = lane >> 4;
    const float scale = 0.17677669529663687f;

    // load Q tile (scaled) -> bf16
    #pragma unroll
    for (int i = 0; i < 2; ++i) {
        int e = t + i * 256; int row = e >> 3, c4 = e & 7;
        int qn = q0 + row;
        float4 xv = make_float4(0.f, 0.f, 0.f, 0.f);
        if (qn < NQ) xv = *(const float4*)&q[((size_t)qn * BS + b) * D + h * DH + c4 * 4];
        uint2 pk;
        pk.x = (unsigned)f2bf(xv.x * scale) | ((unsigned)f2bf(xv.y * scale) << 16);
        pk.y = (unsigned)f2bf(xv.z * scale) | ((unsigned)f2bf(xv.w * scale) << 16);
        *(uint2*)&Qs[row * 40 + c4 * 4] = pk;
    }
    float m_run[4], l_run[4];
    #pragma unroll
    for (int r = 0; r < 4; ++r) { m_run[r] = -1e30f; l_run[r] = 0.f; }
    f32x4 oacc[2];
    oacc[0] = (f32x4){0.f, 0.f, 0.f, 0.f};
    oacc[1] = (f32x4){0.f, 0.f, 0.f, 0.f};
    __syncthreads();

    for (int k0 = 0; k0 < NQ; k0 += 64) {
        // stage K tile
        #pragma unroll
        for (int i = 0; i < 2; ++i) {
            int e = t + i * 256; int row = e >> 3, c4 = e & 7;
            int kn = k0 + row;
            float4 xv = make_float4(0.f, 0.f, 0.f, 0.f);
            if (kn < NQ) xv = *(const float4*)&k[((size_t)kn * BS + b) * D + h * DH + c4 * 4];
            uint2 pk;
            pk.x = (unsigned)f2bf(xv.x) | ((unsigned)f2bf(xv.y) << 16);
            pk.y = (unsigned)f2bf(xv.z) | ((unsigned)f2bf(xv.w) << 16);
            *(uint2*)&Ks[row * 40 + c4 * 4] = pk;
        }
        // stage V tile transposed: Vt[d][kidx]
        #pragma unroll
        for (int i = 0; i < 2; ++i) {
            int e = t + i * 256; int kidx = e >> 3, c4 = e & 7;
            int kn = k0 + kidx;
            float4 xv = make_float4(0.f, 0.f, 0.f, 0.f);
            if (kn < NQ) xv = *(const float4*)&v[((size_t)kn * BS + b) * D + h * DH + c4 * 4];
            Vt[(c4 * 4 + 0) * 72 + kidx] = f2bf(xv.x);
            Vt[(c4 * 4 + 1) * 72 + kidx] = f2bf(xv.y);
            Vt[(c4 * 4 + 2) * 72 + kidx] = f2bf(xv.z);
            Vt[(c4 * 4 + 3) * 72 + kidx] = f2bf(xv.w);
        }
        __syncthreads();

        // QK^T: S[16 q][64 kidx] per wave
        bf16x8 aq = *(const bf16x8*)&Qs[(w * 16 + l15) * 40 + kb * 8];
        f32x4 sacc[4];
        #pragma unroll
        for (int j = 0; j < 4; ++j) {
            bf16x8 bk = *(const bf16x8*)&Ks[(j * 16 + l15) * 40 + kb * 8];
            sacc[j] = __builtin_amdgcn_mfma_f32_16x16x32_bf16(
                aq, bk, (f32x4){0.f, 0.f, 0.f, 0.f}, 0, 0, 0);
        }
        // mask key tail
        int kvalid = NQ - k0;
        #pragma unroll
        for (int j = 0; j < 4; ++j)
            if (j * 16 + l15 >= kvalid) {
                #pragma unroll
                for (int r = 0; r < 4; ++r) sacc[j][r] = -1e30f;
            }
        // row max across 16 lanes (lane&15 varies within group)
        float tm[4];
        #pragma unroll
        for (int r = 0; r < 4; ++r)
            tm[r] = fmaxf(fmaxf(sacc[0][r], sacc[1][r]), fmaxf(sacc[2][r], sacc[3][r]));
        #pragma unroll
        for (int msk = 1; msk <= 8; msk <<= 1)
            #pragma unroll
            for (int r = 0; r < 4; ++r) tm[r] = fmaxf(tm[r], __shfl_xor(tm[r], msk));
        float scl[4], newm[4];
        #pragma unroll
        for (int r = 0; r < 4; ++r) {
            newm[r] = fmaxf(m_run[r], tm[r]);
            scl[r] = __expf(m_run[r] - newm[r]);
            m_run[r] = newm[r];
        }
        // P = exp(S - newm), row sums, write P (bf16) to per-wave LDS
        float ps[4] = {0.f, 0.f, 0.f, 0.f};
        #pragma unroll
        for (int j = 0; j < 4; ++j) {
            #pragma unroll
            for (int r = 0; r < 4; ++r) {
                float p = __expf(sacc[j][r] - newm[r]);
                ps[r] += p;
                Pw[w * 1152 + (kb * 4 + r) * 72 + j * 16 + l15] = f2bf(p);
            }
        }
        #pragma unroll
        for (int msk = 1; msk <= 8; msk <<= 1)
            #pragma unroll
            for (int r = 0; r < 4; ++r) ps[r] += __shfl_xor(ps[r], msk);
        #pragma unroll
        for (int r = 0; r < 4; ++r) l_run[r] = l_run[r] * scl[r] + ps[r];
        // rescale O
        #pragma unroll
        for (int df = 0; df < 2; ++df)
            #pragma unroll
            for (int r = 0; r < 4; ++r) oacc[df][r] *= scl[r];
        // PV: O[16 q][32 d] += P[16][64] x V[64][32]
        #pragma unroll
        for (int hf = 0; hf < 2; ++hf) {
            bf16x8 pa = *(const bf16x8*)&Pw[w * 1152 + l15 * 72 + hf * 32 + kb * 8];
            #pragma unroll
            for (int df = 0; df < 2; ++df) {
                bf16x8 vb = *(const bf16x8*)&Vt[(df * 16 + l15) * 72 + hf * 32 + kb * 8];
                oacc[df] = __builtin_amdgcn_mfma_f32_16x16x32_bf16(pa, vb, oacc[df], 0, 0, 0);
            }
        }
        __syncthreads();
    }
    // store: row = kb*4+r (wave-local q), col = df*16 + l15 (d)
    #pragma unroll
    for (int df = 0; df < 2; ++df) {
        #pragma unroll
        for (int r = 0; r < 4; ++r) {
            int qg = q0 + w * 16 + kb * 4 + r;
            if (qg < NQ)
                o[((size_t)qg * BS + b) * D + h * DH + df * 16 + l15] =
                    oacc[df][r] / l_run[r];
        }
    }
}

// ---------------- out = LayerNorm(x + y) * g + beta ----------------
__global__ void add_ln_kernel(const float* __restrict__ x, const float* __restrict__ y,
                              const float* __restrict__ g, const float* __restrict__ bt,
                              float* __restrict__ out) {
    int m = blockIdx.x, t = threadIdx.x;
    __shared__ float red[8];
    float v = x[m * D + t] + y[m * D + t];
    int lane = t & 63, wid = t >> 6;
    float s = v;
    for (int off = 32; off; off >>= 1) s += __shfl_down(s, off);
    if (lane == 0) red[wid] = s;
    __syncthreads();
    if (t == 0) red[4] = (red[0] + red[1] + red[2] + red[3]) * (1.f / D);
    __syncthreads();
    float mu = red[4];
    float d = v - mu;
    float s2 = d * d;
    __syncthreads();
    for (int off = 32; off; off >>= 1) s2 += __shfl_down(s2, off);
    if (lane == 0) red[wid] = s2;
    __syncthreads();
    if (t == 0) red[5] = rsqrtf((red[0] + red[1] + red[2] + red[3]) * (1.f / D) + 1e-5f);
    __syncthreads();
    out[m * D + t] = d * red[5] * g[t] + bt[t];
}

// ---------------- softmax over NL*NP=16 per (m,h), in place ----------------
__global__ void aw_softmax_kernel(float* __restrict__ aw) {
    int i = blockIdx.x * blockDim.x + threadIdx.x;
    if (i >= MROWS * NH) return;
    float* p = aw + (size_t)i * 16;
    float mx = p[0];
    #pragma unroll
    for (int j = 1; j < 16; ++j) mx = fmaxf(mx, p[j]);
    float e[16], s = 0.f;
    #pragma unroll
    for (int j = 0; j < 16; ++j) { e[j] = __expf(p[j] - mx); s += e[j]; }
    float inv = 1.f / s;
    #pragma unroll
    for (int j = 0; j < 16; ++j) p[j] = e[j] * inv;
}

// ---------------- deformable sampling ----------------
__global__ void deform_kernel(const float* __restrict__ value, const float* __restrict__ offs,
                              const float* __restrict__ aw, const float* __restrict__ refp,
                              const int* __restrict__ shapes, const int* __restrict__ lsi,
                              float* __restrict__ out) {
    int n = blockIdx.x, b = blockIdx.y;
    int t = threadIdx.x, h = t >> 5, dh = t & 31;
    int m = n * BS + b;
    float acc = 0.f;
    #pragma unroll
    for (int l = 0; l < NL; ++l) {
        int Hl = shapes[l * 2], Wl = shapes[l * 2 + 1], s = lsi[l];
        float Wf = (float)Wl, Hf = (float)Hl;
        float rx = refp[(m * NL + l) * 2 + 0];
        float ry = refp[(m * NL + l) * 2 + 1];
        #pragma unroll
        for (int p = 0; p < NP; ++p) {
            int oc = ((h * NL + l) * NP + p) * 2;
            float ox = offs[m * 256 + oc];
            float oy = offs[m * 256 + oc + 1];
            float ww = aw[m * 128 + (h * NL + l) * NP + p];
            float x = (rx + ox / Wf) * Wf - 0.5f;
            float y = (ry + oy / Hf) * Hf - 0.5f;
            float x0 = floorf(x), y0 = floorf(y);
            float lx = x - x0, ly = y - y0;
            int xi = (int)x0, yi = (int)y0;
            #pragma unroll
            for (int cy = 0; cy < 2; ++cy) {
                #pragma unroll
                for (int cx = 0; cx < 2; ++cx) {
                    int xx = xi + cx, yy = yi + cy;
                    if (xx >= 0 && xx < Wl && yy >= 0 && yy < Hl) {
                        float cw = (cx ? lx : 1.f - lx) * (cy ? ly : 1.f - ly);
                        acc += ww * cw * value[((size_t)(s + yy * Wl + xx) * BS + b) * D + h * DH + dh];
                    }
                }
            }
        }
    }
    out[m * D + h * DH + dh] = acc;
}

extern "C" void kernel_launch(void* const* d_in, const int* in_sizes, int n_in,
                              void* d_out, int out_size, void* d_ws, size_t ws_size,
                              hipStream_t stream) {
    const float* tgt    = (const float*)d_in[0];
    const float* pos    = (const float*)d_in[1];
    const float* refp   = (const float*)d_in[2];
    const float* memory = (const float*)d_in[3];
    const int*   shapes = (const int*)d_in[4];
    const int*   lsi    = (const int*)d_in[5];
    const float* sa_wq = (const float*)d_in[6],  *sa_bq = (const float*)d_in[7];
    const float* sa_wk = (const float*)d_in[8],  *sa_bk = (const float*)d_in[9];
    const float* sa_wv = (const float*)d_in[10], *sa_bv = (const float*)d_in[11];
    const float* sa_wo = (const float*)d_in[12], *sa_bo = (const float*)d_in[13];
    const float* ln2_g = (const float*)d_in[14], *ln2_b = (const float*)d_in[15];
    const float* ca_wval = (const float*)d_in[16], *ca_bval = (const float*)d_in[17];
    const float* ca_woff = (const float*)d_in[18], *ca_boff = (const float*)d_in[19];
    const float* ca_wattn = (const float*)d_in[20], *ca_battn = (const float*)d_in[21];
    const float* ca_wout = (const float*)d_in[22], *ca_bout = (const float*)d_in[23];
    const float* ln1_g = (const float*)d_in[24], *ln1_b = (const float*)d_in[25];
    const float* ffn_w1 = (const float*)d_in[26], *ffn_b1 = (const float*)d_in[27];
    const float* ffn_w2 = (const float*)d_in[28], *ffn_b2 = (const float*)d_in[29];
    const float* ln3_g = (const float*)d_in[30], *ln3_b = (const float*)d_in[31];
    float* out = (float*)d_out;

    // ---- workspace: bf16 weight area first, then f32 buffers ----
    ushort* wt = (ushort*)d_ws;
    ushort* wtq   = wt + 0;
    ushort* wtk   = wt + 65536;
    ushort* wtv   = wt + 131072;
    ushort* wto   = wt + 196608;
    ushort* wtval = wt + 262144;
    ushort* wtoff = wt + 327680;
    ushort* wtattn= wt + 393216;   // 32768
    ushort* wtout = wt + 425984;
    ushort* wtf1  = wt + 491520;   // 262144  [1024][256]
    ushort* wtf2  = wt + 753664;   // 262144  [256][1024]
    float* ws = (float*)d_ws + 507904;
    size_t off = 0;
    auto alloc = [&](size_t n) { float* p = ws + off; off += n; return p; };
    const size_t MD = (size_t)MROWS * D;
    float* x    = alloc(MD);
    float* q    = alloc(MD);
    float* k    = alloc(MD);
    float* v    = alloc(MD);
    float* o    = alloc(MD);
    float* tgt1 = alloc(MD);
    float* tgt2 = alloc(MD);
    float* value = alloc((size_t)LV * BS * D);
    (void)ws_size; (void)in_sizes; (void)n_in; (void)out_size;

    dim3 b256(256);

    // ---- preamble: transpose+convert all weights ----
    wt_transpose_kernel<<<dim3(256, 1, 10), b256, 0, stream>>>(
        sa_wq, sa_wk, sa_wv, sa_wo, ca_wval, ca_woff, ca_wattn, ca_wout, ffn_w1, ffn_w2,
        wtq, wtk, wtv, wto, wtval, wtoff, wtattn, wtout, wtf1, wtf2);

    // ---- self attention ----
    add_kernel<<<dim3((MD + 255) / 256), b256, 0, stream>>>(tgt, pos, x, (int)MD);
    gemm_mfma_kernel<false><<<dim3(2, 29), b256, 0, stream>>>(x, wtq, sa_bq, q, MROWS, D, D);
    gemm_mfma_kernel<false><<<dim3(2, 29), b256, 0, stream>>>(x, wtk, sa_bk, k, MROWS, D, D);
    gemm_mfma_kernel<false><<<dim3(2, 29), b256, 0, stream>>>(tgt, wtv, sa_bv, v, MROWS, D, D);
    sa_mfma_kernel<<<dim3(15, NH, BS), b256, 0, stream>>>(q, k, v, o);
    gemm_mfma_kernel<false><<<dim3(2, 29), b256, 0, stream>>>(o, wto, sa_bo, x, MROWS, D, D);
    add_ln_kernel<<<dim3(MROWS), b256, 0, stream>>>(tgt, x, ln2_g, ln2_b, tgt1);

    // ---- MSDeformAttn cross attention ----
    add_kernel<<<dim3((MD + 255) / 256), b256, 0, stream>>>(tgt1, pos, o, (int)MD);  // query -> o
    gemm_mfma_kernel<false><<<dim3(2, 416), b256, 0, stream>>>(memory, wtval, ca_bval, value, LV * BS, D, D);
    gemm_mfma_kernel<false><<<dim3(2, 29), b256, 0, stream>>>(o, wtoff, ca_boff, k, MROWS, D, 256);
    gemm_mfma_kernel<false><<<dim3(1, 29), b256, 0, stream>>>(o, wtattn, ca_battn, v, MROWS, D, 128);
    aw_softmax_kernel<<<dim3((MROWS * NH + 255) / 256), b256, 0, stream>>>(v);
    deform_kernel<<<dim3(NQ, BS), b256, 0, stream>>>(value, k, v, refp, shapes, lsi, q);
    gemm_mfma_kernel<false><<<dim3(2, 29), b256, 0, stream>>>(q, wtout, ca_bout, x, MROWS, D, D);
    add_ln_kernel<<<dim3(MROWS), b256, 0, stream>>>(tgt1, x, ln1_g, ln1_b, tgt2);

    // ---- FFN ----
    gemm_mfma_kernel<true><<<dim3(8, 29), b256, 0, stream>>>(tgt2, wtf1, ffn_b1, value, MROWS, D, DFF);
    gemm_mfma_kernel<false><<<dim3(2, 29), b256, 0, stream>>>(value, wtf2, ffn_b2, o, MROWS, DFF, D);
    add_ln_kernel<<<dim3(MROWS), b256, 0, stream>>>(tgt2, o, ln3_g, ln3_b, out);
}

// Round 6
// 236.254 us; speedup vs baseline: 6.0022x; 1.6458x over previous
//
#include <hip/hip_runtime.h>

#define D    256
#define NH   8
#define DH   32
#define NL   4
#define NP   4
#define DFF  1024
#define NQ   900
#define BS   4
#define LV   13294
#define MROWS (NQ*BS)   // 3600

typedef short bf16x8 __attribute__((ext_vector_type(8)));
typedef float f32x4  __attribute__((ext_vector_type(4)));

__device__ inline ushort f2bf(float f) {
    unsigned u = __float_as_uint(f);
    unsigned r = (u + 0x7fffu + ((u >> 16) & 1u)) >> 16;
    return (ushort)r;
}
__device__ inline float bf2f(ushort u) { return __uint_as_float(((unsigned)u) << 16); }

// ---------------- prep: x_bf = bf(tgt+pos), tgt_bf = bf(tgt) ----------------
__global__ void prep_x_kernel(const float* __restrict__ tgt, const float* __restrict__ pos,
                              ushort* __restrict__ x_bf, ushort* __restrict__ tgt_bf) {
    int i = blockIdx.x * blockDim.x + threadIdx.x;
    float4 a = *(const float4*)&tgt[(size_t)i * 4];
    float4 p = *(const float4*)&pos[(size_t)i * 4];
    ushort4 xo, to;
    to.x = f2bf(a.x); to.y = f2bf(a.y); to.z = f2bf(a.z); to.w = f2bf(a.w);
    xo.x = f2bf(a.x + p.x); xo.y = f2bf(a.y + p.y); xo.z = f2bf(a.z + p.z); xo.w = f2bf(a.w + p.w);
    *(ushort4*)&x_bf[(size_t)i * 4] = xo;
    *(ushort4*)&tgt_bf[(size_t)i * 4] = to;
}

// ---------------- weight transpose+convert: W[K][N] f32 -> Wt[N][K] bf16 ----------------
__global__ void wt_transpose_kernel(
    const float* w0, const float* w1, const float* w2, const float* w3, const float* w4,
    const float* w5, const float* w6, const float* w7, const float* w8, const float* w9,
    ushort* o0, ushort* o1, ushort* o2, ushort* o3, ushort* o4,
    ushort* o5, ushort* o6, ushort* o7, ushort* o8, ushort* o9) {
    __shared__ float Ts[32][33];
    int z = blockIdx.z;
    const float* src; ushort* dst; int K, N;
    switch (z) {
        case 0: src = w0; dst = o0; K = 256;  N = 256;  break;
        case 1: src = w1; dst = o1; K = 256;  N = 256;  break;
        case 2: src = w2; dst = o2; K = 256;  N = 256;  break;
        case 3: src = w3; dst = o3; K = 256;  N = 256;  break;
        case 4: src = w4; dst = o4; K = 256;  N = 256;  break;
        case 5: src = w5; dst = o5; K = 256;  N = 256;  break;
        case 6: src = w6; dst = o6; K = 256;  N = 128;  break;
        case 7: src = w7; dst = o7; K = 256;  N = 256;  break;
        case 8: src = w8; dst = o8; K = 256;  N = 1024; break;
        default:src = w9; dst = o9; K = 1024; N = 256;  break;
    }
    int tiles_n = N >> 5;
    int tile = blockIdx.x;
    int tx = tile % tiles_n, ty = tile / tiles_n;
    if (ty >= (K >> 5)) return;
    int n0 = tx * 32, k0 = ty * 32;
    int t = threadIdx.x;
    #pragma unroll
    for (int i = 0; i < 4; ++i) {
        int e = t + i * 256; int r = e >> 5, c = e & 31;
        Ts[r][c] = src[(size_t)(k0 + r) * N + n0 + c];
    }
    __syncthreads();
    #pragma unroll
    for (int i = 0; i < 4; ++i) {
        int e = t + i * 256; int r = e >> 5, c = e & 31;
        dst[(size_t)(n0 + r) * K + k0 + c] = f2bf(Ts[c][r]);
    }
}

// ---------------- bf16 MFMA GEMM: Y[M,N] = X[M,K] @ Wt[N,K]^T + bias ----------------
struct Job {
    const ushort* Xb;
    const float*  Xf;
    const ushort* Wt;
    const float*  bias;
    float*  Yf;
    ushort* Yb;
    int M, K, N, relu;
};

__global__ __launch_bounds__(256, 3)
void gemm_bf_kernel(Job j0, Job j1, Job j2) {
    Job j = (blockIdx.z == 0) ? j0 : (blockIdx.z == 1 ? j1 : j2);
    const int row0 = blockIdx.y * 64, col0 = blockIdx.x * 64;
    if (row0 >= j.M || col0 >= j.N) return;
    __shared__ ushort As[64 * 72];
    __shared__ ushort Bs[64 * 72];
    const int t = threadIdx.x, w = t >> 6, lane = t & 63;
    const int wr = w >> 1, wc = w & 1, l15 = lane & 15, kb = lane >> 4;

    f32x4 acc[2][2];
    #pragma unroll
    for (int i = 0; i < 2; ++i)
        #pragma unroll
        for (int jj = 0; jj < 2; ++jj) acc[i][jj] = (f32x4){0.f, 0.f, 0.f, 0.f};

    uint4 ra0, ra1, rb0, rb1;
    float4 rf0, rf1, rf2, rf3;

    auto gload = [&](int k0) {
        if (j.Xb) {
            {
                int e = t;              int row = e >> 3, c = e & 7;
                int gr = row0 + row; if (gr >= j.M) gr = j.M - 1;
                ra0 = *(const uint4*)&j.Xb[(size_t)gr * j.K + k0 + c * 8];
            }
            {
                int e = t + 256;        int row = e >> 3, c = e & 7;
                int gr = row0 + row; if (gr >= j.M) gr = j.M - 1;
                ra1 = *(const uint4*)&j.Xb[(size_t)gr * j.K + k0 + c * 8];
            }
        } else {
            {
                int e = t;              int row = e >> 4, q = e & 15;
                int gr = row0 + row; if (gr >= j.M) gr = j.M - 1;
                rf0 = *(const float4*)&j.Xf[(size_t)gr * j.K + k0 + q * 4];
            }
            {
                int e = t + 256;        int row = e >> 4, q = e & 15;
                int gr = row0 + row; if (gr >= j.M) gr = j.M - 1;
                rf1 = *(const float4*)&j.Xf[(size_t)gr * j.K + k0 + q * 4];
            }
            {
                int e = t + 512;        int row = e >> 4, q = e & 15;
                int gr = row0 + row; if (gr >= j.M) gr = j.M - 1;
                rf2 = *(const float4*)&j.Xf[(size_t)gr * j.K + k0 + q * 4];
            }
            {
                int e = t + 768;        int row = e >> 4, q = e & 15;
                int gr = row0 + row; if (gr >= j.M) gr = j.M - 1;
                rf3 = *(const float4*)&j.Xf[(size_t)gr * j.K + k0 + q * 4];
            }
        }
        {
            int e = t;                  int row = e >> 3, c = e & 7;
            rb0 = *(const uint4*)&j.Wt[(size_t)(col0 + row) * j.K + k0 + c * 8];
        }
        {
            int e = t + 256;            int row = e >> 3, c = e & 7;
            rb1 = *(const uint4*)&j.Wt[(size_t)(col0 + row) * j.K + k0 + c * 8];
        }
    };
    auto cvt4 = [](float4 f) {
        ushort4 pk;
        pk.x = f2bf(f.x); pk.y = f2bf(f.y); pk.z = f2bf(f.z); pk.w = f2bf(f.w);
        return pk;
    };
    auto lwrite = [&]() {
        if (j.Xb) {
            { int e = t;       int row = e >> 3, c = e & 7; *(uint4*)&As[row * 72 + c * 8] = ra0; }
            { int e = t + 256; int row = e >> 3, c = e & 7; *(uint4*)&As[row * 72 + c * 8] = ra1; }
        } else {
            { int e = t;       int row = e >> 4, q = e & 15; *(ushort4*)&As[row * 72 + q * 4] = cvt4(rf0); }
            { int e = t + 256; int row = e >> 4, q = e & 15; *(ushort4*)&As[row * 72 + q * 4] = cvt4(rf1); }
            { int e = t + 512; int row = e >> 4, q = e & 15; *(ushort4*)&As[row * 72 + q * 4] = cvt4(rf2); }
            { int e = t + 768; int row = e >> 4, q = e & 15; *(ushort4*)&As[row * 72 + q * 4] = cvt4(rf3); }
        }
        { int e = t;       int row = e >> 3, c = e & 7; *(uint4*)&Bs[row * 72 + c * 8] = rb0; }
        { int e = t + 256; int row = e >> 3, c = e & 7; *(uint4*)&Bs[row * 72 + c * 8] = rb1; }
    };
    auto compute = [&]() {
        bf16x8 a[2][2], b[2][2];
        #pragma unroll
        for (int i = 0; i < 2; ++i)
            #pragma unroll
            for (int kh = 0; kh < 2; ++kh)
                a[i][kh] = *(const bf16x8*)&As[(wr * 32 + i * 16 + l15) * 72 + (kh * 4 + kb) * 8];
        #pragma unroll
        for (int jj = 0; jj < 2; ++jj)
            #pragma unroll
            for (int kh = 0; kh < 2; ++kh)
                b[jj][kh] = *(const bf16x8*)&Bs[(wc * 32 + jj * 16 + l15) * 72 + (kh * 4 + kb) * 8];
        #pragma unroll
        for (int kh = 0; kh < 2; ++kh)
            #pragma unroll
            for (int i = 0; i < 2; ++i)
                #pragma unroll
                for (int jj = 0; jj < 2; ++jj)
                    acc[i][jj] = __builtin_amdgcn_mfma_f32_16x16x32_bf16(
                        a[i][kh], b[jj][kh], acc[i][jj], 0, 0, 0);
    };

    gload(0);
    lwrite();
    __syncthreads();
    const int nt = j.K >> 6;
    for (int tt = 0; tt < nt; ++tt) {
        if (tt + 1 < nt) gload((tt + 1) << 6);
        compute();
        __syncthreads();
        if (tt + 1 < nt) { lwrite(); __syncthreads(); }
    }

    #pragma unroll
    for (int i = 0; i < 2; ++i) {
        #pragma unroll
        for (int jj = 0; jj < 2; ++jj) {
            int gcol = col0 + wc * 32 + jj * 16 + l15;
            float bv = j.bias[gcol];
            #pragma unroll
            for (int r = 0; r < 4; ++r) {
                int grow = row0 + wr * 32 + i * 16 + kb * 4 + r;
                if (grow < j.M) {
                    float vv = acc[i][jj][r] + bv;
                    if (j.relu) vv = fmaxf(vv, 0.f);
                    if (j.Yf) j.Yf[(size_t)grow * j.N + gcol] = vv;
                    if (j.Yb) j.Yb[(size_t)grow * j.N + gcol] = f2bf(vv);
                }
            }
        }
    }
}

// ---------------- MFMA flash self-attention (bf16 in/out) ----------------
__global__ __launch_bounds__(256, 2)
void sa_mfma_kernel(const ushort* __restrict__ q, const ushort* __restrict__ k,
                    const ushort* __restrict__ v, ushort* __restrict__ o) {
    __shared__ ushort Qs[64 * 40];
    __shared__ ushort Ks[64 * 40];
    __shared__ ushort Vt[32 * 72];
    __shared__ ushort Pw[4 * 16 * 72];
    const int qt = blockIdx.x, h = blockIdx.y, b = blockIdx.z;
    const int q0 = qt * 64, t = threadIdx.x;
    const int w = t >> 6, lane = t & 63;
    const int l15 = lane & 15, kb = lane >> 4;
    const float scale = 0.17677669529663687f;

    {
        // 4 threads per row, each loads 8 bf16 (uint4 = 16 B) at slot c*8
        int row = t >> 2, c = t & 3;
        int qn = min(q0 + row, NQ - 1);
        *(uint4*)&Qs[row * 40 + c * 8] =
            *(const uint4*)&q[((size_t)qn * BS + b) * D + h * DH + c * 8];
    }
    float m_run[4], l_run[4];
    #pragma unroll
    for (int r = 0; r < 4; ++r) { m_run[r] = -1e30f; l_run[r] = 0.f; }
    f32x4 oacc[2];
    oacc[0] = (f32x4){0.f, 0.f, 0.f, 0.f};
    oacc[1] = (f32x4){0.f, 0.f, 0.f, 0.f};
    __syncthreads();

    for (int k0 = 0; k0 < NQ; k0 += 64) {
        {
            int row = t >> 2, c = t & 3;
            int kn = min(k0 + row, NQ - 1);
            *(uint4*)&Ks[row * 40 + c * 8] =
                *(const uint4*)&k[((size_t)kn * BS + b) * D + h * DH + c * 8];
            uint4 vv = *(const uint4*)&v[((size_t)kn * BS + b) * D + h * DH + c * 8];
            ushort* pv = (ushort*)&vv;
            #pragma unroll
            for (int u = 0; u < 8; ++u) Vt[(c * 8 + u) * 72 + row] = pv[u];
        }
        __syncthreads();

        bf16x8 aq = *(const bf16x8*)&Qs[(w * 16 + l15) * 40 + kb * 8];
        f32x4 sacc[4];
        #pragma unroll
        for (int jj = 0; jj < 4; ++jj) {
            bf16x8 bk = *(const bf16x8*)&Ks[(jj * 16 + l15) * 40 + kb * 8];
            sacc[jj] = __builtin_amdgcn_mfma_f32_16x16x32_bf16(
                aq, bk, (f32x4){0.f, 0.f, 0.f, 0.f}, 0, 0, 0);
        }
        int kvalid = NQ - k0;
        #pragma unroll
        for (int jj = 0; jj < 4; ++jj) {
            #pragma unroll
            for (int r = 0; r < 4; ++r) sacc[jj][r] *= scale;
            if (jj * 16 + l15 >= kvalid) {
                #pragma unroll
                for (int r = 0; r < 4; ++r) sacc[jj][r] = -1e30f;
            }
        }
        float tm[4];
        #pragma unroll
        for (int r = 0; r < 4; ++r)
            tm[r] = fmaxf(fmaxf(sacc[0][r], sacc[1][r]), fmaxf(sacc[2][r], sacc[3][r]));
        #pragma unroll
        for (int msk = 1; msk <= 8; msk <<= 1)
            #pragma unroll
            for (int r = 0; r < 4; ++r) tm[r] = fmaxf(tm[r], __shfl_xor(tm[r], msk));
        float scl[4], newm[4];
        #pragma unroll
        for (int r = 0; r < 4; ++r) {
            newm[r] = fmaxf(m_run[r], tm[r]);
            scl[r] = __expf(m_run[r] - newm[r]);
            m_run[r] = newm[r];
        }
        float ps[4] = {0.f, 0.f, 0.f, 0.f};
        #pragma unroll
        for (int jj = 0; jj < 4; ++jj) {
            #pragma unroll
            for (int r = 0; r < 4; ++r) {
                float p = __expf(sacc[jj][r] - newm[r]);
                ps[r] += p;
                Pw[w * 1152 + (kb * 4 + r) * 72 + jj * 16 + l15] = f2bf(p);
            }
        }
        #pragma unroll
        for (int msk = 1; msk <= 8; msk <<= 1)
            #pragma unroll
            for (int r = 0; r < 4; ++r) ps[r] += __shfl_xor(ps[r], msk);
        #pragma unroll
        for (int r = 0; r < 4; ++r) l_run[r] = l_run[r] * scl[r] + ps[r];
        #pragma unroll
        for (int df = 0; df < 2; ++df)
            #pragma unroll
            for (int r = 0; r < 4; ++r) oacc[df][r] *= scl[r];
        #pragma unroll
        for (int hf = 0; hf < 2; ++hf) {
            bf16x8 pa = *(const bf16x8*)&Pw[w * 1152 + l15 * 72 + hf * 32 + kb * 8];
            #pragma unroll
            for (int df = 0; df < 2; ++df) {
                bf16x8 vb = *(const bf16x8*)&Vt[(df * 16 + l15) * 72 + hf * 32 + kb * 8];
                oacc[df] = __builtin_amdgcn_mfma_f32_16x16x32_bf16(pa, vb, oacc[df], 0, 0, 0);
            }
        }
        __syncthreads();
    }
    #pragma unroll
    for (int df = 0; df < 2; ++df) {
        #pragma unroll
        for (int r = 0; r < 4; ++r) {
            int qg = q0 + w * 16 + kb * 4 + r;
            if (qg < NQ)
                o[((size_t)qg * BS + b) * D + h * DH + df * 16 + l15] =
                    f2bf(oacc[df][r] / l_run[r]);
        }
    }
}

// ---------------- out = LayerNorm(x + y); MODE 0: f32; 1: +bf16; 2: +bf16(ln+pos) ----------------
template<int MODE>
__global__ void add_ln_kernel(const float* __restrict__ x, const float* __restrict__ y,
                              const float* __restrict__ g, const float* __restrict__ bt,
                              float* __restrict__ outf, ushort* __restrict__ outb,
                              const float* __restrict__ pos) {
    int m = blockIdx.x, t = threadIdx.x;
    __shared__ float red[8];
    float v = x[m * D + t] + y[m * D + t];
    int lane = t & 63, wid = t >> 6;
    float s = v;
    for (int off = 32; off; off >>= 1) s += __shfl_down(s, off);
    if (lane == 0) red[wid] = s;
    __syncthreads();
    if (t == 0) red[4] = (red[0] + red[1] + red[2] + red[3]) * (1.f / D);
    __syncthreads();
    float mu = red[4];
    float d = v - mu;
    float s2 = d * d;
    __syncthreads();
    for (int off = 32; off; off >>= 1) s2 += __shfl_down(s2, off);
    if (lane == 0) red[wid] = s2;
    __syncthreads();
    if (t == 0) red[5] = rsqrtf((red[0] + red[1] + red[2] + red[3]) * (1.f / D) + 1e-5f);
    __syncthreads();
    float res = d * red[5] * g[t] + bt[t];
    outf[m * D + t] = res;
    if (MODE == 1) outb[m * D + t] = f2bf(res);
    if (MODE == 2) outb[m * D + t] = f2bf(res + pos[m * D + t]);
}

// ---------------- softmax over 16 per (m,h), in place ----------------
__global__ void aw_softmax_kernel(float* __restrict__ aw) {
    int i = blockIdx.x * blockDim.x + threadIdx.x;
    if (i >= MROWS * NH) return;
    float* p = aw + (size_t)i * 16;
    float mx = p[0];
    #pragma unroll
    for (int jj = 1; jj < 16; ++jj) mx = fmaxf(mx, p[jj]);
    float e[16], s = 0.f;
    #pragma unroll
    for (int jj = 0; jj < 16; ++jj) { e[jj] = __expf(p[jj] - mx); s += e[jj]; }
    float inv = 1.f / s;
    #pragma unroll
    for (int jj = 0; jj < 16; ++jj) p[jj] = e[jj] * inv;
}

// ---------------- deformable sampling (bf16 value in, bf16 samp out) ----------------
__global__ void deform_kernel(const ushort* __restrict__ value, const float* __restrict__ offs,
                              const float* __restrict__ aw, const float* __restrict__ refp,
                              const int* __restrict__ shapes, const int* __restrict__ lsi,
                              ushort* __restrict__ outb) {
    int n = blockIdx.x, b = blockIdx.y;
    int t = threadIdx.x, h = t >> 5, dh = t & 31;
    int m = n * BS + b;
    float acc = 0.f;
    #pragma unroll
    for (int l = 0; l < NL; ++l) {
        int Hl = shapes[l * 2], Wl = shapes[l * 2 + 1], s = lsi[l];
        float Wf = (float)Wl, Hf = (float)Hl;
        float rx = refp[(m * NL + l) * 2 + 0];
        float ry = refp[(m * NL + l) * 2 + 1];
        #pragma unroll
        for (int p = 0; p < NP; ++p) {
            int oc = ((h * NL + l) * NP + p) * 2;
            float ox = offs[m * 256 + oc];
            float oy = offs[m * 256 + oc + 1];
            float ww = aw[m * 128 + (h * NL + l) * NP + p];
            float x = (rx + ox / Wf) * Wf - 0.5f;
            float y = (ry + oy / Hf) * Hf - 0.5f;
            float x0 = floorf(x), y0 = floorf(y);
            float lx = x - x0, ly = y - y0;
            int xi = (int)x0, yi = (int)y0;
            #pragma unroll
            for (int cy = 0; cy < 2; ++cy) {
                #pragma unroll
                for (int cx = 0; cx < 2; ++cx) {
                    int xx = xi + cx, yy = yi + cy;
                    if (xx >= 0 && xx < Wl && yy >= 0 && yy < Hl) {
                        float cw = (cx ? lx : 1.f - lx) * (cy ? ly : 1.f - ly);
                        acc += ww * cw * bf2f(value[((size_t)(s + yy * Wl + xx) * BS + b) * D + h * DH + dh]);
                    }
                }
            }
        }
    }
    outb[m * D + h * DH + dh] = f2bf(acc);
}

extern "C" void kernel_launch(void* const* d_in, const int* in_sizes, int n_in,
                              void* d_out, int out_size, void* d_ws, size_t ws_size,
                              hipStream_t stream) {
    const float* tgt    = (const float*)d_in[0];
    const float* pos    = (const float*)d_in[1];
    const float* refp   = (const float*)d_in[2];
    const float* memory = (const float*)d_in[3];
    const int*   shapes = (const int*)d_in[4];
    const int*   lsi    = (const int*)d_in[5];
    const float* sa_wq = (const float*)d_in[6],  *sa_bq = (const float*)d_in[7];
    const float* sa_wk = (const float*)d_in[8],  *sa_bk = (const float*)d_in[9];
    const float* sa_wv = (const float*)d_in[10], *sa_bv = (const float*)d_in[11];
    const float* sa_wo = (const float*)d_in[12], *sa_bo = (const float*)d_in[13];
    const float* ln2_g = (const float*)d_in[14], *ln2_b = (const float*)d_in[15];
    const float* ca_wval = (const float*)d_in[16], *ca_bval = (const float*)d_in[17];
    const float* ca_woff = (const float*)d_in[18], *ca_boff = (const float*)d_in[19];
    const float* ca_wattn = (const float*)d_in[20], *ca_battn = (const float*)d_in[21];
    const float* ca_wout = (const float*)d_in[22], *ca_bout = (const float*)d_in[23];
    const float* ln1_g = (const float*)d_in[24], *ln1_b = (const float*)d_in[25];
    const float* ffn_w1 = (const float*)d_in[26], *ffn_b1 = (const float*)d_in[27];
    const float* ffn_w2 = (const float*)d_in[28], *ffn_b2 = (const float*)d_in[29];
    const float* ln3_g = (const float*)d_in[30], *ln3_b = (const float*)d_in[31];
    float* out = (float*)d_out;

    // ---- workspace: bf16 area then f32 area ----
    ushort* wt = (ushort*)d_ws;
    ushort* wtq   = wt + 0;
    ushort* wtk   = wt + 65536;
    ushort* wtv   = wt + 131072;
    ushort* wto   = wt + 196608;
    ushort* wtval = wt + 262144;
    ushort* wtoff = wt + 327680;
    ushort* wtattn= wt + 393216;   // 32768
    ushort* wtout = wt + 425984;
    ushort* wtf1  = wt + 491520;   // 262144
    ushort* wtf2  = wt + 753664;   // 262144  -> ends at 1,015,808
    const size_t MD = (size_t)MROWS * D;  // 921600
    ushort* x_bf   = wt + 1015808;             // aliases: query_bf
    ushort* tgt_bf = x_bf + MD;                // aliases: samp_bf
    ushort* q_bf   = tgt_bf + MD;              // aliases: tgt2_bf
    ushort* k_bf   = q_bf + MD;
    ushort* v_bf   = k_bf + MD;
    ushort* o_bf   = v_bf + MD;
    ushort* value_bf = o_bf + MD;              // LV*BS*D ; aliases: hbuf_bf
    ushort* query_bf = x_bf;
    ushort* samp_bf  = tgt_bf;
    ushort* tgt2_bf  = q_bf;
    ushort* hbuf_bf  = value_bf;
    float* fws = (float*)(value_bf + (size_t)LV * BS * D);
    float* xo   = fws;
    float* tgt1 = xo + MD;
    float* tgt2 = tgt1 + MD;
    float* offs = tgt2 + MD;
    float* aw   = offs + MD;
    (void)ws_size; (void)in_sizes; (void)n_in; (void)out_size;

    dim3 b256(256);
    Job jz = {};
    auto mkb = [](const ushort* Xb, const ushort* Wt, const float* bias,
                  float* Yf, ushort* Yb, int M, int K, int N, int relu) {
        Job j; j.Xb = Xb; j.Xf = nullptr; j.Wt = Wt; j.bias = bias;
        j.Yf = Yf; j.Yb = Yb; j.M = M; j.K = K; j.N = N; j.relu = relu; return j;
    };

    // 1. weights
    wt_transpose_kernel<<<dim3(256, 1, 10), b256, 0, stream>>>(
        sa_wq, sa_wk, sa_wv, sa_wo, ca_wval, ca_woff, ca_wattn, ca_wout, ffn_w1, ffn_w2,
        wtq, wtk, wtv, wto, wtval, wtoff, wtattn, wtout, wtf1, wtf2);
    // 2. activations -> bf16
    prep_x_kernel<<<dim3(MD / 4 / 256), b256, 0, stream>>>(tgt, pos, x_bf, tgt_bf);
    // 3. q,k,v projections (batched)
    gemm_bf_kernel<<<dim3(4, 57, 3), b256, 0, stream>>>(
        mkb(x_bf, wtq, sa_bq, nullptr, q_bf, MROWS, D, D, 0),
        mkb(x_bf, wtk, sa_bk, nullptr, k_bf, MROWS, D, D, 0),
        mkb(tgt_bf, wtv, sa_bv, nullptr, v_bf, MROWS, D, D, 0));
    // 4. self attention
    sa_mfma_kernel<<<dim3(15, NH, BS), b256, 0, stream>>>(q_bf, k_bf, v_bf, o_bf);
    // 5. o-projection
    gemm_bf_kernel<<<dim3(4, 57, 1), b256, 0, stream>>>(
        mkb(o_bf, wto, sa_bo, xo, nullptr, MROWS, D, D, 0), jz, jz);
    // 6. LN2 (+ query_bf = bf(ln + pos))
    add_ln_kernel<2><<<dim3(MROWS), b256, 0, stream>>>(tgt, xo, ln2_g, ln2_b, tgt1, query_bf, pos);
    // 7. value projection (f32 X path)
    {
        Job jv; jv.Xb = nullptr; jv.Xf = memory; jv.Wt = wtval; jv.bias = ca_bval;
        jv.Yf = nullptr; jv.Yb = value_bf; jv.M = LV * BS; jv.K = D; jv.N = D; jv.relu = 0;
        gemm_bf_kernel<<<dim3(4, 831, 1), b256, 0, stream>>>(jv, jz, jz);
    }
    // 8. offsets + attention weights (batched)
    gemm_bf_kernel<<<dim3(4, 57, 2), b256, 0, stream>>>(
        mkb(query_bf, wtoff, ca_boff, offs, nullptr, MROWS, D, 256, 0),
        mkb(query_bf, wtattn, ca_battn, aw, nullptr, MROWS, D, 128, 0), jz);
    // 9. softmax
    aw_softmax_kernel<<<dim3((MROWS * NH + 255) / 256), b256, 0, stream>>>(aw);
    // 10. deformable sampling
    deform_kernel<<<dim3(NQ, BS), b256, 0, stream>>>(value_bf, offs, aw, refp, shapes, lsi, samp_bf);
    // 11. out-projection
    gemm_bf_kernel<<<dim3(4, 57, 1), b256, 0, stream>>>(
        mkb(samp_bf, wtout, ca_bout, xo, nullptr, MROWS, D, D, 0), jz, jz);
    // 12. LN1 (+ tgt2_bf)
    add_ln_kernel<1><<<dim3(MROWS), b256, 0, stream>>>(tgt1, xo, ln1_g, ln1_b, tgt2, tgt2_bf, nullptr);
    // 13. FFN1 (relu, bf16 out)
    gemm_bf_kernel<<<dim3(16, 57, 1), b256, 0, stream>>>(
        mkb(tgt2_bf, wtf1, ffn_b1, nullptr, hbuf_bf, MROWS, D, DFF, 1), jz, jz);
    // 14. FFN2
    gemm_bf_kernel<<<dim3(4, 57, 1), b256, 0, stream>>>(
        mkb(hbuf_bf, wtf2, ffn_b2, xo, nullptr, MROWS, DFF, D, 0), jz, jz);
    // 15. LN3 -> out
    add_ln_kernel<0><<<dim3(MROWS), b256, 0, stream>>>(tgt2, xo, ln3_g, ln3_b, out, nullptr, nullptr);
}

// Round 7
// 225.764 us; speedup vs baseline: 6.2810x; 1.0465x over previous
//
#include <hip/hip_runtime.h>

#define D    256
#define NH   8
#define DH   32
#define NL   4
#define NP   4
#define DFF  1024
#define NQ   900
#define BS   4
#define LV   13294
#define MROWS (NQ*BS)   // 3600

typedef short bf16x8 __attribute__((ext_vector_type(8)));
typedef float f32x4  __attribute__((ext_vector_type(4)));

__device__ inline ushort f2bf(float f) {
    unsigned u = __float_as_uint(f);
    unsigned r = (u + 0x7fffu + ((u >> 16) & 1u)) >> 16;
    return (ushort)r;
}
__device__ inline float bf2f(ushort u) { return __uint_as_float(((unsigned)u) << 16); }

// ---------------- prep: x_bf = bf(tgt+pos), tgt_bf = bf(tgt) ----------------
__global__ void prep_x_kernel(const float* __restrict__ tgt, const float* __restrict__ pos,
                              ushort* __restrict__ x_bf, ushort* __restrict__ tgt_bf) {
    int i = blockIdx.x * blockDim.x + threadIdx.x;
    float4 a = *(const float4*)&tgt[(size_t)i * 4];
    float4 p = *(const float4*)&pos[(size_t)i * 4];
    ushort4 xo, to;
    to.x = f2bf(a.x); to.y = f2bf(a.y); to.z = f2bf(a.z); to.w = f2bf(a.w);
    xo.x = f2bf(a.x + p.x); xo.y = f2bf(a.y + p.y); xo.z = f2bf(a.z + p.z); xo.w = f2bf(a.w + p.w);
    *(ushort4*)&x_bf[(size_t)i * 4] = xo;
    *(ushort4*)&tgt_bf[(size_t)i * 4] = to;
}

// ---------------- weight transpose+convert: W[K][N] f32 -> Wt[N][K] bf16 ----------------
__global__ void wt_transpose_kernel(
    const float* w0, const float* w1, const float* w2, const float* w3, const float* w4,
    const float* w5, const float* w6, const float* w7, const float* w8, const float* w9,
    ushort* o0, ushort* o1, ushort* o2, ushort* o3, ushort* o4,
    ushort* o5, ushort* o6, ushort* o7, ushort* o8, ushort* o9) {
    __shared__ float Ts[32][33];
    int z = blockIdx.z;
    const float* src; ushort* dst; int K, N;
    switch (z) {
        case 0: src = w0; dst = o0; K = 256;  N = 256;  break;
        case 1: src = w1; dst = o1; K = 256;  N = 256;  break;
        case 2: src = w2; dst = o2; K = 256;  N = 256;  break;
        case 3: src = w3; dst = o3; K = 256;  N = 256;  break;
        case 4: src = w4; dst = o4; K = 256;  N = 256;  break;
        case 5: src = w5; dst = o5; K = 256;  N = 256;  break;
        case 6: src = w6; dst = o6; K = 256;  N = 128;  break;
        case 7: src = w7; dst = o7; K = 256;  N = 256;  break;
        case 8: src = w8; dst = o8; K = 256;  N = 1024; break;
        default:src = w9; dst = o9; K = 1024; N = 256;  break;
    }
    int tiles_n = N >> 5;
    int tile = blockIdx.x;
    int tx = tile % tiles_n, ty = tile / tiles_n;
    if (ty >= (K >> 5)) return;
    int n0 = tx * 32, k0 = ty * 32;
    int t = threadIdx.x;
    #pragma unroll
    for (int i = 0; i < 4; ++i) {
        int e = t + i * 256; int r = e >> 5, c = e & 31;
        Ts[r][c] = src[(size_t)(k0 + r) * N + n0 + c];
    }
    __syncthreads();
    #pragma unroll
    for (int i = 0; i < 4; ++i) {
        int e = t + i * 256; int r = e >> 5, c = e & 31;
        dst[(size_t)(n0 + r) * K + k0 + c] = f2bf(Ts[c][r]);
    }
}

// ---------------- bf16 MFMA GEMM: Y[M,N] = X[M,K] @ Wt[N,K]^T + bias ----------------
struct Job {
    const ushort* Xb;
    const float*  Xf;
    const ushort* Wt;
    const float*  bias;
    float*  Yf;
    ushort* Yb;
    int M, K, N, relu;
};

__global__ __launch_bounds__(256, 3)
void gemm_bf_kernel(Job j0, Job j1, Job j2) {
    Job j = (blockIdx.z == 0) ? j0 : (blockIdx.z == 1 ? j1 : j2);
    const int row0 = blockIdx.y * 64, col0 = blockIdx.x * 64;
    if (row0 >= j.M || col0 >= j.N) return;
    __shared__ ushort As[64 * 72];
    __shared__ ushort Bs[64 * 72];
    const int t = threadIdx.x, w = t >> 6, lane = t & 63;
    const int wr = w >> 1, wc = w & 1, l15 = lane & 15, kb = lane >> 4;

    f32x4 acc[2][2];
    #pragma unroll
    for (int i = 0; i < 2; ++i)
        #pragma unroll
        for (int jj = 0; jj < 2; ++jj) acc[i][jj] = (f32x4){0.f, 0.f, 0.f, 0.f};

    uint4 ra0, ra1, rb0, rb1;
    float4 rf0, rf1, rf2, rf3;

    auto gload = [&](int k0) {
        if (j.Xb) {
            {
                int e = t;              int row = e >> 3, c = e & 7;
                int gr = row0 + row; if (gr >= j.M) gr = j.M - 1;
                ra0 = *(const uint4*)&j.Xb[(size_t)gr * j.K + k0 + c * 8];
            }
            {
                int e = t + 256;        int row = e >> 3, c = e & 7;
                int gr = row0 + row; if (gr >= j.M) gr = j.M - 1;
                ra1 = *(const uint4*)&j.Xb[(size_t)gr * j.K + k0 + c * 8];
            }
        } else {
            {
                int e = t;              int row = e >> 4, q = e & 15;
                int gr = row0 + row; if (gr >= j.M) gr = j.M - 1;
                rf0 = *(const float4*)&j.Xf[(size_t)gr * j.K + k0 + q * 4];
            }
            {
                int e = t + 256;        int row = e >> 4, q = e & 15;
                int gr = row0 + row; if (gr >= j.M) gr = j.M - 1;
                rf1 = *(const float4*)&j.Xf[(size_t)gr * j.K + k0 + q * 4];
            }
            {
                int e = t + 512;        int row = e >> 4, q = e & 15;
                int gr = row0 + row; if (gr >= j.M) gr = j.M - 1;
                rf2 = *(const float4*)&j.Xf[(size_t)gr * j.K + k0 + q * 4];
            }
            {
                int e = t + 768;        int row = e >> 4, q = e & 15;
                int gr = row0 + row; if (gr >= j.M) gr = j.M - 1;
                rf3 = *(const float4*)&j.Xf[(size_t)gr * j.K + k0 + q * 4];
            }
        }
        {
            int e = t;                  int row = e >> 3, c = e & 7;
            rb0 = *(const uint4*)&j.Wt[(size_t)(col0 + row) * j.K + k0 + c * 8];
        }
        {
            int e = t + 256;            int row = e >> 3, c = e & 7;
            rb1 = *(const uint4*)&j.Wt[(size_t)(col0 + row) * j.K + k0 + c * 8];
        }
    };
    auto cvt4 = [](float4 f) {
        ushort4 pk;
        pk.x = f2bf(f.x); pk.y = f2bf(f.y); pk.z = f2bf(f.z); pk.w = f2bf(f.w);
        return pk;
    };
    auto lwrite = [&]() {
        if (j.Xb) {
            { int e = t;       int row = e >> 3, c = e & 7; *(uint4*)&As[row * 72 + c * 8] = ra0; }
            { int e = t + 256; int row = e >> 3, c = e & 7; *(uint4*)&As[row * 72 + c * 8] = ra1; }
        } else {
            { int e = t;       int row = e >> 4, q = e & 15; *(ushort4*)&As[row * 72 + q * 4] = cvt4(rf0); }
            { int e = t + 256; int row = e >> 4, q = e & 15; *(ushort4*)&As[row * 72 + q * 4] = cvt4(rf1); }
            { int e = t + 512; int row = e >> 4, q = e & 15; *(ushort4*)&As[row * 72 + q * 4] = cvt4(rf2); }
            { int e = t + 768; int row = e >> 4, q = e & 15; *(ushort4*)&As[row * 72 + q * 4] = cvt4(rf3); }
        }
        { int e = t;       int row = e >> 3, c = e & 7; *(uint4*)&Bs[row * 72 + c * 8] = rb0; }
        { int e = t + 256; int row = e >> 3, c = e & 7; *(uint4*)&Bs[row * 72 + c * 8] = rb1; }
    };
    auto compute = [&]() {
        bf16x8 a[2][2], b[2][2];
        #pragma unroll
        for (int i = 0; i < 2; ++i)
            #pragma unroll
            for (int kh = 0; kh < 2; ++kh)
                a[i][kh] = *(const bf16x8*)&As[(wr * 32 + i * 16 + l15) * 72 + (kh * 4 + kb) * 8];
        #pragma unroll
        for (int jj = 0; jj < 2; ++jj)
            #pragma unroll
            for (int kh = 0; kh < 2; ++kh)
                b[jj][kh] = *(const bf16x8*)&Bs[(wc * 32 + jj * 16 + l15) * 72 + (kh * 4 + kb) * 8];
        #pragma unroll
        for (int kh = 0; kh < 2; ++kh)
            #pragma unroll
            for (int i = 0; i < 2; ++i)
                #pragma unroll
                for (int jj = 0; jj < 2; ++jj)
                    acc[i][jj] = __builtin_amdgcn_mfma_f32_16x16x32_bf16(
                        a[i][kh], b[jj][kh], acc[i][jj], 0, 0, 0);
    };

    gload(0);
    lwrite();
    __syncthreads();
    const int nt = j.K >> 6;
    for (int tt = 0; tt < nt; ++tt) {
        if (tt + 1 < nt) gload((tt + 1) << 6);
        compute();
        __syncthreads();
        if (tt + 1 < nt) { lwrite(); __syncthreads(); }
    }

    #pragma unroll
    for (int i = 0; i < 2; ++i) {
        #pragma unroll
        for (int jj = 0; jj < 2; ++jj) {
            int gcol = col0 + wc * 32 + jj * 16 + l15;
            float bv = j.bias[gcol];
            #pragma unroll
            for (int r = 0; r < 4; ++r) {
                int grow = row0 + wr * 32 + i * 16 + kb * 4 + r;
                if (grow < j.M) {
                    float vv = acc[i][jj][r] + bv;
                    if (j.relu) vv = fmaxf(vv, 0.f);
                    if (j.Yf) j.Yf[(size_t)grow * j.N + gcol] = vv;
                    if (j.Yb) j.Yb[(size_t)grow * j.N + gcol] = f2bf(vv);
                }
            }
        }
    }
}

// ---------------- wide GEMM for value projection: Y[M,256] = X[M,256](f32) @ Wt^T ----------------
// 64 rows x 256 cols per block, 512 threads (8 waves, 2x4 of 32x64), BK=64.
// Full N per block -> each X panel fetched exactly once.
__global__ __launch_bounds__(512, 2)
void gemm_wide_kernel(const float* __restrict__ Xf, const ushort* __restrict__ Wt,
                      const float* __restrict__ bias, ushort* __restrict__ Yb, int M) {
    __shared__ ushort As[64 * 72];
    __shared__ ushort Bs[256 * 72];
    const int t = threadIdx.x, w = t >> 6, lane = t & 63;
    const int wr = w >> 2, wc = w & 3, l15 = lane & 15, kb = lane >> 4;
    const int row0 = blockIdx.x * 64;

    f32x4 acc[2][4];
    #pragma unroll
    for (int i = 0; i < 2; ++i)
        #pragma unroll
        for (int jj = 0; jj < 4; ++jj) acc[i][jj] = (f32x4){0.f, 0.f, 0.f, 0.f};

    float4 rf0, rf1;
    uint4 rb[4];

    auto gload = [&](int k0) {
        {
            int e = t;        int row = e >> 4, q = e & 15;
            int gr = row0 + row; if (gr >= M) gr = M - 1;
            rf0 = *(const float4*)&Xf[(size_t)gr * 256 + k0 + q * 4];
        }
        {
            int e = t + 512;  int row = e >> 4, q = e & 15;
            int gr = row0 + row; if (gr >= M) gr = M - 1;
            rf1 = *(const float4*)&Xf[(size_t)gr * 256 + k0 + q * 4];
        }
        #pragma unroll
        for (int i = 0; i < 4; ++i) {
            int e = t + i * 512; int row = e >> 3, c = e & 7;
            rb[i] = *(const uint4*)&Wt[(size_t)row * 256 + k0 + c * 8];
        }
    };
    auto cvt4 = [](float4 f) {
        ushort4 pk;
        pk.x = f2bf(f.x); pk.y = f2bf(f.y); pk.z = f2bf(f.z); pk.w = f2bf(f.w);
        return pk;
    };
    auto lwrite = [&]() {
        { int e = t;       int row = e >> 4, q = e & 15; *(ushort4*)&As[row * 72 + q * 4] = cvt4(rf0); }
        { int e = t + 512; int row = e >> 4, q = e & 15; *(ushort4*)&As[row * 72 + q * 4] = cvt4(rf1); }
        #pragma unroll
        for (int i = 0; i < 4; ++i) {
            int e = t + i * 512; int row = e >> 3, c = e & 7;
            *(uint4*)&Bs[row * 72 + c * 8] = rb[i];
        }
    };
    auto compute = [&]() {
        bf16x8 a[2][2], b[4][2];
        #pragma unroll
        for (int i = 0; i < 2; ++i)
            #pragma unroll
            for (int kh = 0; kh < 2; ++kh)
                a[i][kh] = *(const bf16x8*)&As[(wr * 32 + i * 16 + l15) * 72 + (kh * 4 + kb) * 8];
        #pragma unroll
        for (int jj = 0; jj < 4; ++jj)
            #pragma unroll
            for (int kh = 0; kh < 2; ++kh)
                b[jj][kh] = *(const bf16x8*)&Bs[(wc * 64 + jj * 16 + l15) * 72 + (kh * 4 + kb) * 8];
        #pragma unroll
        for (int kh = 0; kh < 2; ++kh)
            #pragma unroll
            for (int i = 0; i < 2; ++i)
                #pragma unroll
                for (int jj = 0; jj < 4; ++jj)
                    acc[i][jj] = __builtin_amdgcn_mfma_f32_16x16x32_bf16(
                        a[i][kh], b[jj][kh], acc[i][jj], 0, 0, 0);
    };

    gload(0);
    lwrite();
    __syncthreads();
    #pragma unroll
    for (int tt = 0; tt < 4; ++tt) {
        if (tt + 1 < 4) gload((tt + 1) << 6);
        compute();
        __syncthreads();
        if (tt + 1 < 4) { lwrite(); __syncthreads(); }
    }

    #pragma unroll
    for (int i = 0; i < 2; ++i) {
        #pragma unroll
        for (int jj = 0; jj < 4; ++jj) {
            int gcol = wc * 64 + jj * 16 + l15;
            float bv = bias[gcol];
            #pragma unroll
            for (int r = 0; r < 4; ++r) {
                int grow = row0 + wr * 32 + i * 16 + kb * 4 + r;
                if (grow < M) {
                    Yb[(size_t)grow * 256 + gcol] = f2bf(acc[i][jj][r] + bv);
                }
            }
        }
    }
}

// ---------------- MFMA flash self-attention (bf16 in/out) ----------------
__global__ __launch_bounds__(256, 2)
void sa_mfma_kernel(const ushort* __restrict__ q, const ushort* __restrict__ k,
                    const ushort* __restrict__ v, ushort* __restrict__ o) {
    __shared__ ushort Qs[64 * 40];
    __shared__ ushort Ks[64 * 40];
    __shared__ ushort Vt[32 * 72];
    __shared__ ushort Pw[4 * 16 * 72];
    const int qt = blockIdx.x, h = blockIdx.y, b = blockIdx.z;
    const int q0 = qt * 64, t = threadIdx.x;
    const int w = t >> 6, lane = t & 63;
    const int l15 = lane & 15, kb = lane >> 4;
    const float scale = 0.17677669529663687f;

    {
        int row = t >> 2, c = t & 3;
        int qn = min(q0 + row, NQ - 1);
        *(uint4*)&Qs[row * 40 + c * 8] =
            *(const uint4*)&q[((size_t)qn * BS + b) * D + h * DH + c * 8];
    }
    float m_run[4], l_run[4];
    #pragma unroll
    for (int r = 0; r < 4; ++r) { m_run[r] = -1e30f; l_run[r] = 0.f; }
    f32x4 oacc[2];
    oacc[0] = (f32x4){0.f, 0.f, 0.f, 0.f};
    oacc[1] = (f32x4){0.f, 0.f, 0.f, 0.f};
    __syncthreads();

    for (int k0 = 0; k0 < NQ; k0 += 64) {
        {
            int row = t >> 2, c = t & 3;
            int kn = min(k0 + row, NQ - 1);
            *(uint4*)&Ks[row * 40 + c * 8] =
                *(const uint4*)&k[((size_t)kn * BS + b) * D + h * DH + c * 8];
            uint4 vv = *(const uint4*)&v[((size_t)kn * BS + b) * D + h * DH + c * 8];
            ushort* pv = (ushort*)&vv;
            #pragma unroll
            for (int u = 0; u < 8; ++u) Vt[(c * 8 + u) * 72 + row] = pv[u];
        }
        __syncthreads();

        bf16x8 aq = *(const bf16x8*)&Qs[(w * 16 + l15) * 40 + kb * 8];
        f32x4 sacc[4];
        #pragma unroll
        for (int jj = 0; jj < 4; ++jj) {
            bf16x8 bk = *(const bf16x8*)&Ks[(jj * 16 + l15) * 40 + kb * 8];
            sacc[jj] = __builtin_amdgcn_mfma_f32_16x16x32_bf16(
                aq, bk, (f32x4){0.f, 0.f, 0.f, 0.f}, 0, 0, 0);
        }
        int kvalid = NQ - k0;
        #pragma unroll
        for (int jj = 0; jj < 4; ++jj) {
            #pragma unroll
            for (int r = 0; r < 4; ++r) sacc[jj][r] *= scale;
            if (jj * 16 + l15 >= kvalid) {
                #pragma unroll
                for (int r = 0; r < 4; ++r) sacc[jj][r] = -1e30f;
            }
        }
        float tm[4];
        #pragma unroll
        for (int r = 0; r < 4; ++r)
            tm[r] = fmaxf(fmaxf(sacc[0][r], sacc[1][r]), fmaxf(sacc[2][r], sacc[3][r]));
        #pragma unroll
        for (int msk = 1; msk <= 8; msk <<= 1)
            #pragma unroll
            for (int r = 0; r < 4; ++r) tm[r] = fmaxf(tm[r], __shfl_xor(tm[r], msk));
        float scl[4], newm[4];
        #pragma unroll
        for (int r = 0; r < 4; ++r) {
            newm[r] = fmaxf(m_run[r], tm[r]);
            scl[r] = __expf(m_run[r] - newm[r]);
            m_run[r] = newm[r];
        }
        float ps[4] = {0.f, 0.f, 0.f, 0.f};
        #pragma unroll
        for (int jj = 0; jj < 4; ++jj) {
            #pragma unroll
            for (int r = 0; r < 4; ++r) {
                float p = __expf(sacc[jj][r] - newm[r]);
                ps[r] += p;
                Pw[w * 1152 + (kb * 4 + r) * 72 + jj * 16 + l15] = f2bf(p);
            }
        }
        #pragma unroll
        for (int msk = 1; msk <= 8; msk <<= 1)
            #pragma unroll
            for (int r = 0; r < 4; ++r) ps[r] += __shfl_xor(ps[r], msk);
        #pragma unroll
        for (int r = 0; r < 4; ++r) l_run[r] = l_run[r] * scl[r] + ps[r];
        #pragma unroll
        for (int df = 0; df < 2; ++df)
            #pragma unroll
            for (int r = 0; r < 4; ++r) oacc[df][r] *= scl[r];
        #pragma unroll
        for (int hf = 0; hf < 2; ++hf) {
            bf16x8 pa = *(const bf16x8*)&Pw[w * 1152 + l15 * 72 + hf * 32 + kb * 8];
            #pragma unroll
            for (int df = 0; df < 2; ++df) {
                bf16x8 vb = *(const bf16x8*)&Vt[(df * 16 + l15) * 72 + hf * 32 + kb * 8];
                oacc[df] = __builtin_amdgcn_mfma_f32_16x16x32_bf16(pa, vb, oacc[df], 0, 0, 0);
            }
        }
        __syncthreads();
    }
    #pragma unroll
    for (int df = 0; df < 2; ++df) {
        #pragma unroll
        for (int r = 0; r < 4; ++r) {
            int qg = q0 + w * 16 + kb * 4 + r;
            if (qg < NQ)
                o[((size_t)qg * BS + b) * D + h * DH + df * 16 + l15] =
                    f2bf(oacc[df][r] / l_run[r]);
        }
    }
}

// ---------------- out = LayerNorm(x + y); MODE 0: f32; 1: +bf16; 2: +bf16(ln+pos) ----------------
template<int MODE>
__global__ void add_ln_kernel(const float* __restrict__ x, const float* __restrict__ y,
                              const float* __restrict__ g, const float* __restrict__ bt,
                              float* __restrict__ outf, ushort* __restrict__ outb,
                              const float* __restrict__ pos) {
    int m = blockIdx.x, t = threadIdx.x;
    __shared__ float red[8];
    float v = x[m * D + t] + y[m * D + t];
    int lane = t & 63, wid = t >> 6;
    float s = v;
    for (int off = 32; off; off >>= 1) s += __shfl_down(s, off);
    if (lane == 0) red[wid] = s;
    __syncthreads();
    if (t == 0) red[4] = (red[0] + red[1] + red[2] + red[3]) * (1.f / D);
    __syncthreads();
    float mu = red[4];
    float d = v - mu;
    float s2 = d * d;
    __syncthreads();
    for (int off = 32; off; off >>= 1) s2 += __shfl_down(s2, off);
    if (lane == 0) red[wid] = s2;
    __syncthreads();
    if (t == 0) red[5] = rsqrtf((red[0] + red[1] + red[2] + red[3]) * (1.f / D) + 1e-5f);
    __syncthreads();
    float res = d * red[5] * g[t] + bt[t];
    outf[m * D + t] = res;
    if (MODE == 1) outb[m * D + t] = f2bf(res);
    if (MODE == 2) outb[m * D + t] = f2bf(res + pos[m * D + t]);
}

// ---------------- deformable sampling (softmax fused; bf16 value in/out) ----------------
__global__ void deform_kernel(const ushort* __restrict__ value, const float* __restrict__ offs,
                              const float* __restrict__ aw, const float* __restrict__ refp,
                              const int* __restrict__ shapes, const int* __restrict__ lsi,
                              ushort* __restrict__ outb) {
    int n = blockIdx.x, b = blockIdx.y;
    int t = threadIdx.x, h = t >> 5, dh = t & 31;
    int m = n * BS + b;
    __shared__ float awn[NH * 16];
    if (t < NH) {
        const float* p = aw + (size_t)m * 128 + t * 16;
        float mx = p[0];
        #pragma unroll
        for (int jj = 1; jj < 16; ++jj) mx = fmaxf(mx, p[jj]);
        float e[16], s = 0.f;
        #pragma unroll
        for (int jj = 0; jj < 16; ++jj) { e[jj] = __expf(p[jj] - mx); s += e[jj]; }
        float inv = 1.f / s;
        #pragma unroll
        for (int jj = 0; jj < 16; ++jj) awn[t * 16 + jj] = e[jj] * inv;
    }
    __syncthreads();
    float acc = 0.f;
    #pragma unroll
    for (int l = 0; l < NL; ++l) {
        int Hl = shapes[l * 2], Wl = shapes[l * 2 + 1], s = lsi[l];
        float Wf = (float)Wl, Hf = (float)Hl;
        float rx = refp[(m * NL + l) * 2 + 0];
        float ry = refp[(m * NL + l) * 2 + 1];
        #pragma unroll
        for (int p = 0; p < NP; ++p) {
            int oc = ((h * NL + l) * NP + p) * 2;
            float ox = offs[m * 256 + oc];
            float oy = offs[m * 256 + oc + 1];
            float ww = awn[h * 16 + l * NP + p];
            float x = (rx + ox / Wf) * Wf - 0.5f;
            float y = (ry + oy / Hf) * Hf - 0.5f;
            float x0 = floorf(x), y0 = floorf(y);
            float lx = x - x0, ly = y - y0;
            int xi = (int)x0, yi = (int)y0;
            #pragma unroll
            for (int cy = 0; cy < 2; ++cy) {
                #pragma unroll
                for (int cx = 0; cx < 2; ++cx) {
                    int xx = xi + cx, yy = yi + cy;
                    if (xx >= 0 && xx < Wl && yy >= 0 && yy < Hl) {
                        float cw = (cx ? lx : 1.f - lx) * (cy ? ly : 1.f - ly);
                        acc += ww * cw * bf2f(value[((size_t)(s + yy * Wl + xx) * BS + b) * D + h * DH + dh]);
                    }
                }
            }
        }
    }
    outb[m * D + h * DH + dh] = f2bf(acc);
}

extern "C" void kernel_launch(void* const* d_in, const int* in_sizes, int n_in,
                              void* d_out, int out_size, void* d_ws, size_t ws_size,
                              hipStream_t stream) {
    const float* tgt    = (const float*)d_in[0];
    const float* pos    = (const float*)d_in[1];
    const float* refp   = (const float*)d_in[2];
    const float* memory = (const float*)d_in[3];
    const int*   shapes = (const int*)d_in[4];
    const int*   lsi    = (const int*)d_in[5];
    const float* sa_wq = (const float*)d_in[6],  *sa_bq = (const float*)d_in[7];
    const float* sa_wk = (const float*)d_in[8],  *sa_bk = (const float*)d_in[9];
    const float* sa_wv = (const float*)d_in[10], *sa_bv = (const float*)d_in[11];
    const float* sa_wo = (const float*)d_in[12], *sa_bo = (const float*)d_in[13];
    const float* ln2_g = (const float*)d_in[14], *ln2_b = (const float*)d_in[15];
    const float* ca_wval = (const float*)d_in[16], *ca_bval = (const float*)d_in[17];
    const float* ca_woff = (const float*)d_in[18], *ca_boff = (const float*)d_in[19];
    const float* ca_wattn = (const float*)d_in[20], *ca_battn = (const float*)d_in[21];
    const float* ca_wout = (const float*)d_in[22], *ca_bout = (const float*)d_in[23];
    const float* ln1_g = (const float*)d_in[24], *ln1_b = (const float*)d_in[25];
    const float* ffn_w1 = (const float*)d_in[26], *ffn_b1 = (const float*)d_in[27];
    const float* ffn_w2 = (const float*)d_in[28], *ffn_b2 = (const float*)d_in[29];
    const float* ln3_g = (const float*)d_in[30], *ln3_b = (const float*)d_in[31];
    float* out = (float*)d_out;

    // ---- workspace: bf16 area then f32 area ----
    ushort* wt = (ushort*)d_ws;
    ushort* wtq   = wt + 0;
    ushort* wtk   = wt + 65536;
    ushort* wtv   = wt + 131072;
    ushort* wto   = wt + 196608;
    ushort* wtval = wt + 262144;
    ushort* wtoff = wt + 327680;
    ushort* wtattn= wt + 393216;   // 32768
    ushort* wtout = wt + 425984;
    ushort* wtf1  = wt + 491520;   // 262144
    ushort* wtf2  = wt + 753664;   // 262144  -> ends at 1,015,808
    const size_t MD = (size_t)MROWS * D;  // 921600
    ushort* x_bf   = wt + 1015808;             // aliases: query_bf
    ushort* tgt_bf = x_bf + MD;                // aliases: samp_bf
    ushort* q_bf   = tgt_bf + MD;              // aliases: tgt2_bf
    ushort* k_bf   = q_bf + MD;
    ushort* v_bf   = k_bf + MD;
    ushort* o_bf   = v_bf + MD;
    ushort* value_bf = o_bf + MD;              // LV*BS*D ; aliases: hbuf_bf
    ushort* query_bf = x_bf;
    ushort* samp_bf  = tgt_bf;
    ushort* tgt2_bf  = q_bf;
    ushort* hbuf_bf  = value_bf;
    float* fws = (float*)(value_bf + (size_t)LV * BS * D);
    float* xo   = fws;
    float* tgt1 = xo + MD;
    float* tgt2 = tgt1 + MD;
    float* offs = tgt2 + MD;
    float* aw   = offs + MD;
    (void)ws_size; (void)in_sizes; (void)n_in; (void)out_size;

    dim3 b256(256);
    Job jz = {};
    auto mkb = [](const ushort* Xb, const ushort* Wt, const float* bias,
                  float* Yf, ushort* Yb, int M, int K, int N, int relu) {
        Job j; j.Xb = Xb; j.Xf = nullptr; j.Wt = Wt; j.bias = bias;
        j.Yf = Yf; j.Yb = Yb; j.M = M; j.K = K; j.N = N; j.relu = relu; return j;
    };

    // 1. weights
    wt_transpose_kernel<<<dim3(256, 1, 10), b256, 0, stream>>>(
        sa_wq, sa_wk, sa_wv, sa_wo, ca_wval, ca_woff, ca_wattn, ca_wout, ffn_w1, ffn_w2,
        wtq, wtk, wtv, wto, wtval, wtoff, wtattn, wtout, wtf1, wtf2);
    // 2. activations -> bf16
    prep_x_kernel<<<dim3(MD / 4 / 256), b256, 0, stream>>>(tgt, pos, x_bf, tgt_bf);
    // 3. q,k,v projections (batched)
    gemm_bf_kernel<<<dim3(4, 57, 3), b256, 0, stream>>>(
        mkb(x_bf, wtq, sa_bq, nullptr, q_bf, MROWS, D, D, 0),
        mkb(x_bf, wtk, sa_bk, nullptr, k_bf, MROWS, D, D, 0),
        mkb(tgt_bf, wtv, sa_bv, nullptr, v_bf, MROWS, D, D, 0));
    // 4. self attention
    sa_mfma_kernel<<<dim3(15, NH, BS), b256, 0, stream>>>(q_bf, k_bf, v_bf, o_bf);
    // 5. o-projection
    gemm_bf_kernel<<<dim3(4, 57, 1), b256, 0, stream>>>(
        mkb(o_bf, wto, sa_bo, xo, nullptr, MROWS, D, D, 0), jz, jz);
    // 6. LN2 (+ query_bf = bf(ln + pos))
    add_ln_kernel<2><<<dim3(MROWS), b256, 0, stream>>>(tgt, xo, ln2_g, ln2_b, tgt1, query_bf, pos);
    // 7. value projection: wide tile, X fetched once
    gemm_wide_kernel<<<dim3((LV * BS + 63) / 64), dim3(512), 0, stream>>>(
        memory, wtval, ca_bval, value_bf, LV * BS);
    // 8. offsets + attention weights (batched; aw left raw, softmax fused into deform)
    gemm_bf_kernel<<<dim3(4, 57, 2), b256, 0, stream>>>(
        mkb(query_bf, wtoff, ca_boff, offs, nullptr, MROWS, D, 256, 0),
        mkb(query_bf, wtattn, ca_battn, aw, nullptr, MROWS, D, 128, 0), jz);
    // 9. deformable sampling (softmax inside)
    deform_kernel<<<dim3(NQ, BS), b256, 0, stream>>>(value_bf, offs, aw, refp, shapes, lsi, samp_bf);
    // 10. out-projection
    gemm_bf_kernel<<<dim3(4, 57, 1), b256, 0, stream>>>(
        mkb(samp_bf, wtout, ca_bout, xo, nullptr, MROWS, D, D, 0), jz, jz);
    // 11. LN1 (+ tgt2_bf)
    add_ln_kernel<1><<<dim3(MROWS), b256, 0, stream>>>(tgt1, xo, ln1_g, ln1_b, tgt2, tgt2_bf, nullptr);
    // 12. FFN1 (relu, bf16 out)
    gemm_bf_kernel<<<dim3(16, 57, 1), b256, 0, stream>>>(
        mkb(tgt2_bf, wtf1, ffn_b1, nullptr, hbuf_bf, MROWS, D, DFF, 1), jz, jz);
    // 13. FFN2
    gemm_bf_kernel<<<dim3(4, 57, 1), b256, 0, stream>>>(
        mkb(hbuf_bf, wtf2, ffn_b2, xo, nullptr, MROWS, DFF, D, 0), jz, jz);
    // 14. LN3 -> out
    add_ln_kernel<0><<<dim3(MROWS), b256, 0, stream>>>(tgt2, xo, ln3_g, ln3_b, out, nullptr, nullptr);
}

// Round 8
// 217.332 us; speedup vs baseline: 6.5247x; 1.0388x over previous
//
#include <hip/hip_runtime.h>

#define D    256
#define NH   8
#define DH   32
#define NL   4
#define NP   4
#define DFF  1024
#define NQ   900
#define BS   4
#define LV   13294
#define MROWS (NQ*BS)   // 3600

typedef short bf16x8 __attribute__((ext_vector_type(8)));
typedef float f32x4  __attribute__((ext_vector_type(4)));

__device__ inline ushort f2bf(float f) {
    unsigned u = __float_as_uint(f);
    unsigned r = (u + 0x7fffu + ((u >> 16) & 1u)) >> 16;
    return (ushort)r;
}
__device__ inline float bf2f(ushort u) { return __uint_as_float(((unsigned)u) << 16); }

// ---------------- prep: x_bf = bf(tgt+pos), tgt_bf = bf(tgt) ----------------
__global__ void prep_x_kernel(const float* __restrict__ tgt, const float* __restrict__ pos,
                              ushort* __restrict__ x_bf, ushort* __restrict__ tgt_bf) {
    int i = blockIdx.x * blockDim.x + threadIdx.x;
    float4 a = *(const float4*)&tgt[(size_t)i * 4];
    float4 p = *(const float4*)&pos[(size_t)i * 4];
    ushort4 xo, to;
    to.x = f2bf(a.x); to.y = f2bf(a.y); to.z = f2bf(a.z); to.w = f2bf(a.w);
    xo.x = f2bf(a.x + p.x); xo.y = f2bf(a.y + p.y); xo.z = f2bf(a.z + p.z); xo.w = f2bf(a.w + p.w);
    *(ushort4*)&x_bf[(size_t)i * 4] = xo;
    *(ushort4*)&tgt_bf[(size_t)i * 4] = to;
}

// ---------------- weight transpose+convert: W[K][N] f32 -> Wt[N][K] bf16 ----------------
__global__ void wt_transpose_kernel(
    const float* w0, const float* w1, const float* w2, const float* w3, const float* w4,
    const float* w5, const float* w6, const float* w7, const float* w8, const float* w9,
    ushort* o0, ushort* o1, ushort* o2, ushort* o3, ushort* o4,
    ushort* o5, ushort* o6, ushort* o7, ushort* o8, ushort* o9) {
    __shared__ float Ts[32][33];
    int z = blockIdx.z;
    const float* src; ushort* dst; int K, N;
    switch (z) {
        case 0: src = w0; dst = o0; K = 256;  N = 256;  break;
        case 1: src = w1; dst = o1; K = 256;  N = 256;  break;
        case 2: src = w2; dst = o2; K = 256;  N = 256;  break;
        case 3: src = w3; dst = o3; K = 256;  N = 256;  break;
        case 4: src = w4; dst = o4; K = 256;  N = 256;  break;
        case 5: src = w5; dst = o5; K = 256;  N = 256;  break;
        case 6: src = w6; dst = o6; K = 256;  N = 128;  break;
        case 7: src = w7; dst = o7; K = 256;  N = 256;  break;
        case 8: src = w8; dst = o8; K = 256;  N = 1024; break;
        default:src = w9; dst = o9; K = 1024; N = 256;  break;
    }
    int tiles_n = N >> 5;
    int tile = blockIdx.x;
    int tx = tile % tiles_n, ty = tile / tiles_n;
    if (ty >= (K >> 5)) return;
    int n0 = tx * 32, k0 = ty * 32;
    int t = threadIdx.x;
    #pragma unroll
    for (int i = 0; i < 4; ++i) {
        int e = t + i * 256; int r = e >> 5, c = e & 31;
        Ts[r][c] = src[(size_t)(k0 + r) * N + n0 + c];
    }
    __syncthreads();
    #pragma unroll
    for (int i = 0; i < 4; ++i) {
        int e = t + i * 256; int r = e >> 5, c = e & 31;
        dst[(size_t)(n0 + r) * K + k0 + c] = f2bf(Ts[c][r]);
    }
}

// ---------------- bf16 MFMA GEMM: Y[M,N] = X[M,K] @ Wt[N,K]^T + bias ----------------
struct Job {
    const ushort* Xb;
    const float*  Xf;
    const ushort* Wt;
    const float*  bias;
    float*  Yf;
    ushort* Yb;
    int M, K, N, relu;
};

__global__ __launch_bounds__(256, 3)
void gemm_bf_kernel(Job j0, Job j1, Job j2) {
    Job j = (blockIdx.z == 0) ? j0 : (blockIdx.z == 1 ? j1 : j2);
    const int row0 = blockIdx.y * 64, col0 = blockIdx.x * 64;
    if (row0 >= j.M || col0 >= j.N) return;
    __shared__ ushort As[64 * 72];
    __shared__ ushort Bs[64 * 72];
    const int t = threadIdx.x, w = t >> 6, lane = t & 63;
    const int wr = w >> 1, wc = w & 1, l15 = lane & 15, kb = lane >> 4;

    f32x4 acc[2][2];
    #pragma unroll
    for (int i = 0; i < 2; ++i)
        #pragma unroll
        for (int jj = 0; jj < 2; ++jj) acc[i][jj] = (f32x4){0.f, 0.f, 0.f, 0.f};

    uint4 ra0, ra1, rb0, rb1;
    float4 rf0, rf1, rf2, rf3;

    auto gload = [&](int k0) {
        if (j.Xb) {
            {
                int e = t;              int row = e >> 3, c = e & 7;
                int gr = row0 + row; if (gr >= j.M) gr = j.M - 1;
                ra0 = *(const uint4*)&j.Xb[(size_t)gr * j.K + k0 + c * 8];
            }
            {
                int e = t + 256;        int row = e >> 3, c = e & 7;
                int gr = row0 + row; if (gr >= j.M) gr = j.M - 1;
                ra1 = *(const uint4*)&j.Xb[(size_t)gr * j.K + k0 + c * 8];
            }
        } else {
            {
                int e = t;              int row = e >> 4, q = e & 15;
                int gr = row0 + row; if (gr >= j.M) gr = j.M - 1;
                rf0 = *(const float4*)&j.Xf[(size_t)gr * j.K + k0 + q * 4];
            }
            {
                int e = t + 256;        int row = e >> 4, q = e & 15;
                int gr = row0 + row; if (gr >= j.M) gr = j.M - 1;
                rf1 = *(const float4*)&j.Xf[(size_t)gr * j.K + k0 + q * 4];
            }
            {
                int e = t + 512;        int row = e >> 4, q = e & 15;
                int gr = row0 + row; if (gr >= j.M) gr = j.M - 1;
                rf2 = *(const float4*)&j.Xf[(size_t)gr * j.K + k0 + q * 4];
            }
            {
                int e = t + 768;        int row = e >> 4, q = e & 15;
                int gr = row0 + row; if (gr >= j.M) gr = j.M - 1;
                rf3 = *(const float4*)&j.Xf[(size_t)gr * j.K + k0 + q * 4];
            }
        }
        {
            int e = t;                  int row = e >> 3, c = e & 7;
            rb0 = *(const uint4*)&j.Wt[(size_t)(col0 + row) * j.K + k0 + c * 8];
        }
        {
            int e = t + 256;            int row = e >> 3, c = e & 7;
            rb1 = *(const uint4*)&j.Wt[(size_t)(col0 + row) * j.K + k0 + c * 8];
        }
    };
    auto cvt4 = [](float4 f) {
        ushort4 pk;
        pk.x = f2bf(f.x); pk.y = f2bf(f.y); pk.z = f2bf(f.z); pk.w = f2bf(f.w);
        return pk;
    };
    auto lwrite = [&]() {
        if (j.Xb) {
            { int e = t;       int row = e >> 3, c = e & 7; *(uint4*)&As[row * 72 + c * 8] = ra0; }
            { int e = t + 256; int row = e >> 3, c = e & 7; *(uint4*)&As[row * 72 + c * 8] = ra1; }
        } else {
            { int e = t;       int row = e >> 4, q = e & 15; *(ushort4*)&As[row * 72 + q * 4] = cvt4(rf0); }
            { int e = t + 256; int row = e >> 4, q = e & 15; *(ushort4*)&As[row * 72 + q * 4] = cvt4(rf1); }
            { int e = t + 512; int row = e >> 4, q = e & 15; *(ushort4*)&As[row * 72 + q * 4] = cvt4(rf2); }
            { int e = t + 768; int row = e >> 4, q = e & 15; *(ushort4*)&As[row * 72 + q * 4] = cvt4(rf3); }
        }
        { int e = t;       int row = e >> 3, c = e & 7; *(uint4*)&Bs[row * 72 + c * 8] = rb0; }
        { int e = t + 256; int row = e >> 3, c = e & 7; *(uint4*)&Bs[row * 72 + c * 8] = rb1; }
    };
    auto compute = [&]() {
        bf16x8 a[2][2], b[2][2];
        #pragma unroll
        for (int i = 0; i < 2; ++i)
            #pragma unroll
            for (int kh = 0; kh < 2; ++kh)
                a[i][kh] = *(const bf16x8*)&As[(wr * 32 + i * 16 + l15) * 72 + (kh * 4 + kb) * 8];
        #pragma unroll
        for (int jj = 0; jj < 2; ++jj)
            #pragma unroll
            for (int kh = 0; kh < 2; ++kh)
                b[jj][kh] = *(const bf16x8*)&Bs[(wc * 32 + jj * 16 + l15) * 72 + (kh * 4 + kb) * 8];
        #pragma unroll
        for (int kh = 0; kh < 2; ++kh)
            #pragma unroll
            for (int i = 0; i < 2; ++i)
                #pragma unroll
                for (int jj = 0; jj < 2; ++jj)
                    acc[i][jj] = __builtin_amdgcn_mfma_f32_16x16x32_bf16(
                        a[i][kh], b[jj][kh], acc[i][jj], 0, 0, 0);
    };

    gload(0);
    lwrite();
    __syncthreads();
    const int nt = j.K >> 6;
    for (int tt = 0; tt < nt; ++tt) {
        if (tt + 1 < nt) gload((tt + 1) << 6);
        compute();
        __syncthreads();
        if (tt + 1 < nt) { lwrite(); __syncthreads(); }
    }

    if (j.Yb) {
        // stage bf16 tile in LDS (reuse As), then coalesced uint4 stores
        #pragma unroll
        for (int i = 0; i < 2; ++i) {
            #pragma unroll
            for (int jj = 0; jj < 2; ++jj) {
                int lcol = wc * 32 + jj * 16 + l15;
                float bv = j.bias[col0 + lcol];
                #pragma unroll
                for (int r = 0; r < 4; ++r) {
                    int lrow = wr * 32 + i * 16 + kb * 4 + r;
                    float vv = acc[i][jj][r] + bv;
                    if (j.relu) vv = fmaxf(vv, 0.f);
                    As[lrow * 64 + lcol] = f2bf(vv);
                }
            }
        }
        __syncthreads();
        #pragma unroll
        for (int it = 0; it < 2; ++it) {
            int idx = t + it * 256;            // 512 uint4 = 64 rows x 8
            int lrow = idx >> 3, c = idx & 7;
            int grow = row0 + lrow;
            if (grow < j.M)
                *(uint4*)&j.Yb[(size_t)grow * j.N + col0 + c * 8] =
                    *(const uint4*)&As[lrow * 64 + c * 8];
        }
    } else {
        #pragma unroll
        for (int i = 0; i < 2; ++i) {
            #pragma unroll
            for (int jj = 0; jj < 2; ++jj) {
                int gcol = col0 + wc * 32 + jj * 16 + l15;
                float bv = j.bias[gcol];
                #pragma unroll
                for (int r = 0; r < 4; ++r) {
                    int grow = row0 + wr * 32 + i * 16 + kb * 4 + r;
                    if (grow < j.M) {
                        float vv = acc[i][jj][r] + bv;
                        if (j.relu) vv = fmaxf(vv, 0.f);
                        j.Yf[(size_t)grow * j.N + gcol] = vv;
                    }
                }
            }
        }
    }
}

// ---------------- wide GEMM for value projection: Y[M,256] = X[M,256](f32) @ Wt^T ----------------
__global__ __launch_bounds__(512, 2)
void gemm_wide_kernel(const float* __restrict__ Xf, const ushort* __restrict__ Wt,
                      const float* __restrict__ bias, ushort* __restrict__ Yb, int M) {
    __shared__ ushort As[64 * 72];
    __shared__ ushort Bs[256 * 72];
    const int t = threadIdx.x, w = t >> 6, lane = t & 63;
    const int wr = w >> 2, wc = w & 3, l15 = lane & 15, kb = lane >> 4;
    const int row0 = blockIdx.x * 64;

    f32x4 acc[2][4];
    #pragma unroll
    for (int i = 0; i < 2; ++i)
        #pragma unroll
        for (int jj = 0; jj < 4; ++jj) acc[i][jj] = (f32x4){0.f, 0.f, 0.f, 0.f};

    float4 rf0, rf1;
    uint4 rb[4];

    auto gload = [&](int k0) {
        {
            int e = t;        int row = e >> 4, q = e & 15;
            int gr = row0 + row; if (gr >= M) gr = M - 1;
            rf0 = *(const float4*)&Xf[(size_t)gr * 256 + k0 + q * 4];
        }
        {
            int e = t + 512;  int row = e >> 4, q = e & 15;
            int gr = row0 + row; if (gr >= M) gr = M - 1;
            rf1 = *(const float4*)&Xf[(size_t)gr * 256 + k0 + q * 4];
        }
        #pragma unroll
        for (int i = 0; i < 4; ++i) {
            int e = t + i * 512; int row = e >> 3, c = e & 7;
            rb[i] = *(const uint4*)&Wt[(size_t)row * 256 + k0 + c * 8];
        }
    };
    auto cvt4 = [](float4 f) {
        ushort4 pk;
        pk.x = f2bf(f.x); pk.y = f2bf(f.y); pk.z = f2bf(f.z); pk.w = f2bf(f.w);
        return pk;
    };
    auto lwrite = [&]() {
        { int e = t;       int row = e >> 4, q = e & 15; *(ushort4*)&As[row * 72 + q * 4] = cvt4(rf0); }
        { int e = t + 512; int row = e >> 4, q = e & 15; *(ushort4*)&As[row * 72 + q * 4] = cvt4(rf1); }
        #pragma unroll
        for (int i = 0; i < 4; ++i) {
            int e = t + i * 512; int row = e >> 3, c = e & 7;
            *(uint4*)&Bs[row * 72 + c * 8] = rb[i];
        }
    };
    auto compute = [&]() {
        bf16x8 a[2][2], b[4][2];
        #pragma unroll
        for (int i = 0; i < 2; ++i)
            #pragma unroll
            for (int kh = 0; kh < 2; ++kh)
                a[i][kh] = *(const bf16x8*)&As[(wr * 32 + i * 16 + l15) * 72 + (kh * 4 + kb) * 8];
        #pragma unroll
        for (int jj = 0; jj < 4; ++jj)
            #pragma unroll
            for (int kh = 0; kh < 2; ++kh)
                b[jj][kh] = *(const bf16x8*)&Bs[(wc * 64 + jj * 16 + l15) * 72 + (kh * 4 + kb) * 8];
        #pragma unroll
        for (int kh = 0; kh < 2; ++kh)
            #pragma unroll
            for (int i = 0; i < 2; ++i)
                #pragma unroll
                for (int jj = 0; jj < 4; ++jj)
                    acc[i][jj] = __builtin_amdgcn_mfma_f32_16x16x32_bf16(
                        a[i][kh], b[jj][kh], acc[i][jj], 0, 0, 0);
    };

    gload(0);
    lwrite();
    __syncthreads();
    #pragma unroll
    for (int tt = 0; tt < 4; ++tt) {
        if (tt + 1 < 4) gload((tt + 1) << 6);
        compute();
        __syncthreads();
        if (tt + 1 < 4) { lwrite(); __syncthreads(); }
    }

    // stage 64x256 bf16 output tile in LDS (reuse Bs), then coalesced stores
    ushort* obuf = Bs;
    #pragma unroll
    for (int i = 0; i < 2; ++i) {
        #pragma unroll
        for (int jj = 0; jj < 4; ++jj) {
            int lcol = wc * 64 + jj * 16 + l15;
            float bv = bias[lcol];
            #pragma unroll
            for (int r = 0; r < 4; ++r) {
                int lrow = wr * 32 + i * 16 + kb * 4 + r;
                obuf[lrow * 256 + lcol] = f2bf(acc[i][jj][r] + bv);
            }
        }
    }
    __syncthreads();
    #pragma unroll
    for (int it = 0; it < 4; ++it) {
        int idx = t + it * 512;               // 2048 uint4 = 64 rows x 32
        int lrow = idx >> 5, c = idx & 31;
        int grow = row0 + lrow;
        if (grow < M)
            *(uint4*)&Yb[(size_t)grow * 256 + c * 8] =
                *(const uint4*)&obuf[lrow * 256 + c * 8];
    }
}

// ---------------- MFMA flash self-attention (bf16 in/out) ----------------
__global__ __launch_bounds__(256, 2)
void sa_mfma_kernel(const ushort* __restrict__ q, const ushort* __restrict__ k,
                    const ushort* __restrict__ v, ushort* __restrict__ o) {
    __shared__ ushort Qs[64 * 40];
    __shared__ ushort Ks[64 * 40];
    __shared__ ushort Vt[32 * 72];
    __shared__ ushort Pw[4 * 16 * 72];
    const int qt = blockIdx.x, h = blockIdx.y, b = blockIdx.z;
    const int q0 = qt * 64, t = threadIdx.x;
    const int w = t >> 6, lane = t & 63;
    const int l15 = lane & 15, kb = lane >> 4;
    const float scale = 0.17677669529663687f;

    {
        int row = t >> 2, c = t & 3;
        int qn = min(q0 + row, NQ - 1);
        *(uint4*)&Qs[row * 40 + c * 8] =
            *(const uint4*)&q[((size_t)qn * BS + b) * D + h * DH + c * 8];
    }
    float m_run[4], l_run[4];
    #pragma unroll
    for (int r = 0; r < 4; ++r) { m_run[r] = -1e30f; l_run[r] = 0.f; }
    f32x4 oacc[2];
    oacc[0] = (f32x4){0.f, 0.f, 0.f, 0.f};
    oacc[1] = (f32x4){0.f, 0.f, 0.f, 0.f};
    __syncthreads();

    for (int k0 = 0; k0 < NQ; k0 += 64) {
        {
            int row = t >> 2, c = t & 3;
            int kn = min(k0 + row, NQ - 1);
            *(uint4*)&Ks[row * 40 + c * 8] =
                *(const uint4*)&k[((size_t)kn * BS + b) * D + h * DH + c * 8];
            uint4 vv = *(const uint4*)&v[((size_t)kn * BS + b) * D + h * DH + c * 8];
            ushort* pv = (ushort*)&vv;
            #pragma unroll
            for (int u = 0; u < 8; ++u) Vt[(c * 8 + u) * 72 + row] = pv[u];
        }
        __syncthreads();

        bf16x8 aq = *(const bf16x8*)&Qs[(w * 16 + l15) * 40 + kb * 8];
        f32x4 sacc[4];
        #pragma unroll
        for (int jj = 0; jj < 4; ++jj) {
            bf16x8 bk = *(const bf16x8*)&Ks[(jj * 16 + l15) * 40 + kb * 8];
            sacc[jj] = __builtin_amdgcn_mfma_f32_16x16x32_bf16(
                aq, bk, (f32x4){0.f, 0.f, 0.f, 0.f}, 0, 0, 0);
        }
        int kvalid = NQ - k0;
        #pragma unroll
        for (int jj = 0; jj < 4; ++jj) {
            #pragma unroll
            for (int r = 0; r < 4; ++r) sacc[jj][r] *= scale;
            if (jj * 16 + l15 >= kvalid) {
                #pragma unroll
                for (int r = 0; r < 4; ++r) sacc[jj][r] = -1e30f;
            }
        }
        float tm[4];
        #pragma unroll
        for (int r = 0; r < 4; ++r)
            tm[r] = fmaxf(fmaxf(sacc[0][r], sacc[1][r]), fmaxf(sacc[2][r], sacc[3][r]));
        #pragma unroll
        for (int msk = 1; msk <= 8; msk <<= 1)
            #pragma unroll
            for (int r = 0; r < 4; ++r) tm[r] = fmaxf(tm[r], __shfl_xor(tm[r], msk));
        float scl[4], newm[4];
        #pragma unroll
        for (int r = 0; r < 4; ++r) {
            newm[r] = fmaxf(m_run[r], tm[r]);
            scl[r] = __expf(m_run[r] - newm[r]);
            m_run[r] = newm[r];
        }
        float ps[4] = {0.f, 0.f, 0.f, 0.f};
        #pragma unroll
        for (int jj = 0; jj < 4; ++jj) {
            #pragma unroll
            for (int r = 0; r < 4; ++r) {
                float p = __expf(sacc[jj][r] - newm[r]);
                ps[r] += p;
                Pw[w * 1152 + (kb * 4 + r) * 72 + jj * 16 + l15] = f2bf(p);
            }
        }
        #pragma unroll
        for (int msk = 1; msk <= 8; msk <<= 1)
            #pragma unroll
            for (int r = 0; r < 4; ++r) ps[r] += __shfl_xor(ps[r], msk);
        #pragma unroll
        for (int r = 0; r < 4; ++r) l_run[r] = l_run[r] * scl[r] + ps[r];
        #pragma unroll
        for (int df = 0; df < 2; ++df)
            #pragma unroll
            for (int r = 0; r < 4; ++r) oacc[df][r] *= scl[r];
        #pragma unroll
        for (int hf = 0; hf < 2; ++hf) {
            bf16x8 pa = *(const bf16x8*)&Pw[w * 1152 + l15 * 72 + hf * 32 + kb * 8];
            #pragma unroll
            for (int df = 0; df < 2; ++df) {
                bf16x8 vb = *(const bf16x8*)&Vt[(df * 16 + l15) * 72 + hf * 32 + kb * 8];
                oacc[df] = __builtin_amdgcn_mfma_f32_16x16x32_bf16(pa, vb, oacc[df], 0, 0, 0);
            }
        }
        __syncthreads();
    }
    #pragma unroll
    for (int df = 0; df < 2; ++df) {
        #pragma unroll
        for (int r = 0; r < 4; ++r) {
            int qg = q0 + w * 16 + kb * 4 + r;
            if (qg < NQ)
                o[((size_t)qg * BS + b) * D + h * DH + df * 16 + l15] =
                    f2bf(oacc[df][r] / l_run[r]);
        }
    }
}

// ---------------- out = LayerNorm(x + y); MODE 0: f32; 1: +bf16; 2: +bf16(ln+pos) ----------------
template<int MODE>
__global__ void add_ln_kernel(const float* __restrict__ x, const float* __restrict__ y,
                              const float* __restrict__ g, const float* __restrict__ bt,
                              float* __restrict__ outf, ushort* __restrict__ outb,
                              const float* __restrict__ pos) {
    int m = blockIdx.x, t = threadIdx.x;
    __shared__ float red[8];
    float v = x[m * D + t] + y[m * D + t];
    int lane = t & 63, wid = t >> 6;
    float s = v;
    for (int off = 32; off; off >>= 1) s += __shfl_down(s, off);
    if (lane == 0) red[wid] = s;
    __syncthreads();
    if (t == 0) red[4] = (red[0] + red[1] + red[2] + red[3]) * (1.f / D);
    __syncthreads();
    float mu = red[4];
    float d = v - mu;
    float s2 = d * d;
    __syncthreads();
    for (int off = 32; off; off >>= 1) s2 += __shfl_down(s2, off);
    if (lane == 0) red[wid] = s2;
    __syncthreads();
    if (t == 0) red[5] = rsqrtf((red[0] + red[1] + red[2] + red[3]) * (1.f / D) + 1e-5f);
    __syncthreads();
    float res = d * red[5] * g[t] + bt[t];
    outf[m * D + t] = res;
    if (MODE == 1) outb[m * D + t] = f2bf(res);
    if (MODE == 2) outb[m * D + t] = f2bf(res + pos[m * D + t]);
}

// ---------------- deformable sampling (softmax fused; bf16 value in/out) ----------------
__global__ void deform_kernel(const ushort* __restrict__ value, const float* __restrict__ offs,
                              const float* __restrict__ aw, const float* __restrict__ refp,
                              const int* __restrict__ shapes, const int* __restrict__ lsi,
                              ushort* __restrict__ outb) {
    int n = blockIdx.x, b = blockIdx.y;
    int t = threadIdx.x, h = t >> 5, dh = t & 31;
    int m = n * BS + b;
    __shared__ float awn[NH * 16];
    if (t < NH) {
        const float* p = aw + (size_t)m * 128 + t * 16;
        float mx = p[0];
        #pragma unroll
        for (int jj = 1; jj < 16; ++jj) mx = fmaxf(mx, p[jj]);
        float e[16], s = 0.f;
        #pragma unroll
        for (int jj = 0; jj < 16; ++jj) { e[jj] = __expf(p[jj] - mx); s += e[jj]; }
        float inv = 1.f / s;
        #pragma unroll
        for (int jj = 0; jj < 16; ++jj) awn[t * 16 + jj] = e[jj] * inv;
    }
    __syncthreads();
    float acc = 0.f;
    #pragma unroll
    for (int l = 0; l < NL; ++l) {
        int Hl = shapes[l * 2], Wl = shapes[l * 2 + 1], s = lsi[l];
        float Wf = (float)Wl, Hf = (float)Hl;
        float rx = refp[(m * NL + l) * 2 + 0];
        float ry = refp[(m * NL + l) * 2 + 1];
        #pragma unroll
        for (int p = 0; p < NP; ++p) {
            int oc = ((h * NL + l) * NP + p) * 2;
            float ox = offs[m * 256 + oc];
            float oy = offs[m * 256 + oc + 1];
            float ww = awn[h * 16 + l * NP + p];
            float x = (rx + ox / Wf) * Wf - 0.5f;
            float y = (ry + oy / Hf) * Hf - 0.5f;
            float x0 = floorf(x), y0 = floorf(y);
            float lx = x - x0, ly = y - y0;
            int xi = (int)x0, yi = (int)y0;
            #pragma unroll
            for (int cy = 0; cy < 2; ++cy) {
                #pragma unroll
                for (int cx = 0; cx < 2; ++cx) {
                    int xx = xi + cx, yy = yi + cy;
                    if (xx >= 0 && xx < Wl && yy >= 0 && yy < Hl) {
                        float cw = (cx ? lx : 1.f - lx) * (cy ? ly : 1.f - ly);
                        acc += ww * cw * bf2f(value[((size_t)(s + yy * Wl + xx) * BS + b) * D + h * DH + dh]);
                    }
                }
            }
        }
    }
    outb[m * D + h * DH + dh] = f2bf(acc);
}

extern "C" void kernel_launch(void* const* d_in, const int* in_sizes, int n_in,
                              void* d_out, int out_size, void* d_ws, size_t ws_size,
                              hipStream_t stream) {
    const float* tgt    = (const float*)d_in[0];
    const float* pos    = (const float*)d_in[1];
    const float* refp   = (const float*)d_in[2];
    const float* memory = (const float*)d_in[3];
    const int*   shapes = (const int*)d_in[4];
    const int*   lsi    = (const int*)d_in[5];
    const float* sa_wq = (const float*)d_in[6],  *sa_bq = (const float*)d_in[7];
    const float* sa_wk = (const float*)d_in[8],  *sa_bk = (const float*)d_in[9];
    const float* sa_wv = (const float*)d_in[10], *sa_bv = (const float*)d_in[11];
    const float* sa_wo = (const float*)d_in[12], *sa_bo = (const float*)d_in[13];
    const float* ln2_g = (const float*)d_in[14], *ln2_b = (const float*)d_in[15];
    const float* ca_wval = (const float*)d_in[16], *ca_bval = (const float*)d_in[17];
    const float* ca_woff = (const float*)d_in[18], *ca_boff = (const float*)d_in[19];
    const float* ca_wattn = (const float*)d_in[20], *ca_battn = (const float*)d_in[21];
    const float* ca_wout = (const float*)d_in[22], *ca_bout = (const float*)d_in[23];
    const float* ln1_g = (const float*)d_in[24], *ln1_b = (const float*)d_in[25];
    const float* ffn_w1 = (const float*)d_in[26], *ffn_b1 = (const float*)d_in[27];
    const float* ffn_w2 = (const float*)d_in[28], *ffn_b2 = (const float*)d_in[29];
    const float* ln3_g = (const float*)d_in[30], *ln3_b = (const float*)d_in[31];
    float* out = (float*)d_out;

    // ---- workspace: bf16 area then f32 area ----
    ushort* wt = (ushort*)d_ws;
    ushort* wtq   = wt + 0;
    ushort* wtk   = wt + 65536;
    ushort* wtv   = wt + 131072;
    ushort* wto   = wt + 196608;
    ushort* wtval = wt + 262144;
    ushort* wtoff = wt + 327680;
    ushort* wtattn= wt + 393216;   // 32768
    ushort* wtout = wt + 425984;
    ushort* wtf1  = wt + 491520;   // 262144
    ushort* wtf2  = wt + 753664;   // 262144  -> ends at 1,015,808
    const size_t MD = (size_t)MROWS * D;  // 921600
    ushort* x_bf   = wt + 1015808;             // aliases: query_bf
    ushort* tgt_bf = x_bf + MD;                // aliases: samp_bf
    ushort* q_bf   = tgt_bf + MD;              // aliases: tgt2_bf
    ushort* k_bf   = q_bf + MD;
    ushort* v_bf   = k_bf + MD;
    ushort* o_bf   = v_bf + MD;
    ushort* value_bf = o_bf + MD;              // LV*BS*D ; aliases: hbuf_bf
    ushort* query_bf = x_bf;
    ushort* samp_bf  = tgt_bf;
    ushort* tgt2_bf  = q_bf;
    ushort* hbuf_bf  = value_bf;
    float* fws = (float*)(value_bf + (size_t)LV * BS * D);
    float* xo   = fws;
    float* tgt1 = xo + MD;
    float* tgt2 = tgt1 + MD;
    float* offs = tgt2 + MD;
    float* aw   = offs + MD;
    (void)ws_size; (void)in_sizes; (void)n_in; (void)out_size;

    dim3 b256(256);
    Job jz = {};
    auto mkb = [](const ushort* Xb, const ushort* Wt, const float* bias,
                  float* Yf, ushort* Yb, int M, int K, int N, int relu) {
        Job j; j.Xb = Xb; j.Xf = nullptr; j.Wt = Wt; j.bias = bias;
        j.Yf = Yf; j.Yb = Yb; j.M = M; j.K = K; j.N = N; j.relu = relu; return j;
    };

    // 1. weights
    wt_transpose_kernel<<<dim3(256, 1, 10), b256, 0, stream>>>(
        sa_wq, sa_wk, sa_wv, sa_wo, ca_wval, ca_woff, ca_wattn, ca_wout, ffn_w1, ffn_w2,
        wtq, wtk, wtv, wto, wtval, wtoff, wtattn, wtout, wtf1, wtf2);
    // 2. activations -> bf16
    prep_x_kernel<<<dim3(MD / 4 / 256), b256, 0, stream>>>(tgt, pos, x_bf, tgt_bf);
    // 3. q,k,v projections (batched)
    gemm_bf_kernel<<<dim3(4, 57, 3), b256, 0, stream>>>(
        mkb(x_bf, wtq, sa_bq, nullptr, q_bf, MROWS, D, D, 0),
        mkb(x_bf, wtk, sa_bk, nullptr, k_bf, MROWS, D, D, 0),
        mkb(tgt_bf, wtv, sa_bv, nullptr, v_bf, MROWS, D, D, 0));
    // 4. self attention
    sa_mfma_kernel<<<dim3(15, NH, BS), b256, 0, stream>>>(q_bf, k_bf, v_bf, o_bf);
    // 5. o-projection
    gemm_bf_kernel<<<dim3(4, 57, 1), b256, 0, stream>>>(
        mkb(o_bf, wto, sa_bo, xo, nullptr, MROWS, D, D, 0), jz, jz);
    // 6. LN2 (+ query_bf = bf(ln + pos))
    add_ln_kernel<2><<<dim3(MROWS), b256, 0, stream>>>(tgt, xo, ln2_g, ln2_b, tgt1, query_bf, pos);
    // 7. value projection: wide tile, X fetched once, coalesced output
    gemm_wide_kernel<<<dim3((LV * BS + 63) / 64), dim3(512), 0, stream>>>(
        memory, wtval, ca_bval, value_bf, LV * BS);
    // 8. offsets + attention weights (batched; softmax fused into deform)
    gemm_bf_kernel<<<dim3(4, 57, 2), b256, 0, stream>>>(
        mkb(query_bf, wtoff, ca_boff, offs, nullptr, MROWS, D, 256, 0),
        mkb(query_bf, wtattn, ca_battn, aw, nullptr, MROWS, D, 128, 0), jz);
    // 9. deformable sampling (softmax inside)
    deform_kernel<<<dim3(NQ, BS), b256, 0, stream>>>(value_bf, offs, aw, refp, shapes, lsi, samp_bf);
    // 10. out-projection
    gemm_bf_kernel<<<dim3(4, 57, 1), b256, 0, stream>>>(
        mkb(samp_bf, wtout, ca_bout, xo, nullptr, MROWS, D, D, 0), jz, jz);
    // 11. LN1 (+ tgt2_bf)
    add_ln_kernel<1><<<dim3(MROWS), b256, 0, stream>>>(tgt1, xo, ln1_g, ln1_b, tgt2, tgt2_bf, nullptr);
    // 12. FFN1 (relu, bf16 out)
    gemm_bf_kernel<<<dim3(16, 57, 1), b256, 0, stream>>>(
        mkb(tgt2_bf, wtf1, ffn_b1, nullptr, hbuf_bf, MROWS, D, DFF, 1), jz, jz);
    // 13. FFN2
    gemm_bf_kernel<<<dim3(4, 57, 1), b256, 0, stream>>>(
        mkb(hbuf_bf, wtf2, ffn_b2, xo, nullptr, MROWS, DFF, D, 0), jz, jz);
    // 14. LN3 -> out
    add_ln_kernel<0><<<dim3(MROWS), b256, 0, stream>>>(tgt2, xo, ln3_g, ln3_b, out, nullptr, nullptr);
}